// Round 1
// 995.685 us; speedup vs baseline: 1.0415x; 1.0415x over previous
//
#include <hip/hip_runtime.h>
#include <cstdint>
#include <cstddef>

#define NN 1024
#define EE 2048
#define ETOT 3072
#define HH 32

typedef __bf16 bf16_t;
typedef __attribute__((ext_vector_type(8))) __bf16 bf16x8;
typedef __attribute__((ext_vector_type(4))) __bf16 bf16x4;
typedef __attribute__((ext_vector_type(2))) __bf16 bf16x2;
typedef __attribute__((ext_vector_type(4))) float f32x4;

typedef const __attribute__((address_space(1))) void gvoid_t;
typedef __attribute__((address_space(3))) void lvoid_t;

// async global->LDS, 16B per lane. LDS dest = wave-uniform base + lane*16.
__device__ __forceinline__ void gll16(const void* g, void* l) {
    __builtin_amdgcn_global_load_lds((gvoid_t*)g, (lvoid_t*)l, 16, 0, 0);
}

// ---------------- utility ----------------
__global__ void k_zero_int(int* p, int n) {
    int i = blockIdx.x * 256 + threadIdx.x;
    if (i < n) p[i] = 0;
}

__global__ void k_detect(const int* ei, int* flag) {
    int i = blockIdx.x * 256 + threadIdx.x;
    int idx = 2 * i + 1;
    if (idx < 2 * EE && ei[idx] != 0) atomicOr(flag, 1);
}

__global__ void k_edge_prep(const int* ei, const int* flag, int* srcA, int* dstA, int* cnt) {
    int e = blockIdx.x * 256 + threadIdx.x;
    if (e >= ETOT) return;
    int s, d;
    if (e < EE) {
        if (*flag) { s = ei[e]; d = ei[EE + e]; }
        else       { s = ei[2 * e]; d = ei[2 * (EE + e)]; }
        s &= (NN - 1); d &= (NN - 1);
    } else {
        s = d = e - EE;
    }
    srcA[e] = s; dstA[e] = d;
    atomicAdd(&cnt[d], 1);
}

__global__ void k_scan(const int* cnt, int* off) {
    __shared__ int sh[NN];
    int t = threadIdx.x;
    sh[t] = cnt[t];
    __syncthreads();
    for (int o = 1; o < NN; o <<= 1) {
        int v = (t >= o) ? sh[t - o] : 0;
        __syncthreads();
        sh[t] += v;
        __syncthreads();
    }
    off[t + 1] = sh[t];
    if (t == 0) off[0] = 0;
}

__global__ void k_fill(const int* dstA, const int* off, int* cur, int* csre) {
    int e = blockIdx.x * 256 + threadIdx.x;
    if (e >= ETOT) return;
    int d = dstA[e];
    int p = atomicAdd(&cur[d], 1);
    csre[off[d] + p] = e;
}

// ---------------- fp32 -> bf16 converts ----------------
__global__ void k_convA(const float* __restrict__ A, bf16_t* __restrict__ Ab,
                        int M, int K, int Kp) {
    int idx = blockIdx.x * 256 + threadIdx.x;
    if (idx >= M * Kp) return;
    int m = idx / Kp, k = idx % Kp;
    Ab[idx] = (k < K) ? (bf16_t)A[(size_t)m * K + k] : (bf16_t)0.f;
}

// transpose-convert: B[K][ldb] fp32 -> Bt[Nsub][Kp] bf16. bf16x2 writes (4B/lane).
__global__ void k_convB(const float* __restrict__ B, bf16_t* __restrict__ Bt,
                        int K, int Nsub, int ldb, int Kp) {
    __shared__ float sh[32][33];
    int kt = blockIdx.y * 32, nt = blockIdx.x * 32;
    int tx = threadIdx.x & 31, ty = threadIdx.x >> 5;
#pragma unroll
    for (int i = 0; i < 4; ++i) {
        int k = kt + ty + i * 8, n = nt + tx;
        sh[ty + i * 8][tx] = (k < K && n < Nsub) ? B[(size_t)k * ldb + n] : 0.f;
    }
    __syncthreads();
    int k2 = (threadIdx.x & 15) * 2;   // even k within tile
    int nl = threadIdx.x >> 4;         // 0..15
#pragma unroll
    for (int i = 0; i < 2; ++i) {
        int n = nt + nl + i * 16;
        if (n < Nsub) {
            bf16x2 v;
            v[0] = (bf16_t)sh[k2][nl + i * 16];
            v[1] = (bf16_t)sh[k2 + 1][nl + i * 16];
            *(bf16x2*)(&Bt[(size_t)n * Kp + kt + k2]) = v;
        }
    }
}

// ---------------- bf16 MFMA GEMM (m97 structure) ----------------
// C[M x Nsub] = Ab[M x Kp] @ Bt[Nsub x Kp]^T + bias; output fp32 or bf16 (obf).
// global_load_lds 16B staging into linear [128][32] tiles; 16B-slot XOR swizzle
// applied on the GLOBAL source and undone on the LDS fragment read (rule #21);
// bijective XCD chunk remap so the 8 M-blocks sharing a B-panel co-reside.
__global__ __launch_bounds__(256) void k_gemm_bf16(
        const bf16_t* __restrict__ Ab, const bf16_t* __restrict__ Bt,
        const float* __restrict__ bias, void* __restrict__ Cm,
        int M, int Nsub, int Kp, int act, int obf) {
    __shared__ __align__(16) bf16_t As[128][32];
    __shared__ __align__(16) bf16_t Bs[128][32];
    int tid = threadIdx.x;
    int wave = tid >> 6, lane = tid & 63;
    int wm = (wave & 1) * 64, wn = (wave >> 1) * 64;
    int l16 = lane & 15, lq = lane >> 4;

    // XCD-aware remap (y fastest within each chunk): blocks sharing one
    // B-panel become consecutive in dispatch order -> same XCD L2.
    int nx = gridDim.x, ny = gridDim.y;
    int bx = blockIdx.x, by = blockIdx.y;
    int total = nx * ny;
    if ((total & 7) == 0) {
        int j = bx + nx * by;
        int w = (j & 7) * (total >> 3) + (j >> 3);
        bx = w / ny;
        by = w % ny;
    }
    int m0 = by * 128, n0 = bx * 128;

    // staging: 8KB per tile = 512 x 16B units; unit u -> row r = u>>2, slot u&3.
    // wave w covers units [w*128, w*128+128) via 2 calls (A) + 2 calls (B).
    // global source slot = lds slot ^ ((r>>1)&3)  (involution; undone on read)
    int u0 = wave * 128 + lane;
    int u1 = u0 + 64;
    int r0 = u0 >> 2, s0 = u0 & 3;
    int r1 = u1 >> 2, s1 = u1 & 3;
    int c0 = ((s0 ^ ((r0 >> 1) & 3)) << 3);   // bf16 elements within row
    int c1 = ((s1 ^ ((r1 >> 1) & 3)) << 3);
    const bf16_t* gA0 = Ab + (size_t)(m0 + r0) * Kp + c0;
    const bf16_t* gA1 = Ab + (size_t)(m0 + r1) * Kp + c1;
    const bf16_t* gB0 = Bt + (size_t)(n0 + r0) * Kp + c0;
    const bf16_t* gB1 = Bt + (size_t)(n0 + r1) * Kp + c1;
    bf16_t* lA = &As[0][0] + wave * 1024;     // 2048 B per-wave chunk
    bf16_t* lB = &Bs[0][0] + wave * 1024;

    // fragment-read swizzle (same involution; uniform across mi/ni since
    // row = 16*base + l16 and ((16*base+l16)>>1)&3 == (l16>>1)&3)
    int cR = ((lq ^ ((l16 >> 1) & 3)) << 3);

    f32x4 acc[4][4] = {};

    for (int k0 = 0; k0 < Kp; k0 += 32) {
        gll16(gA0, lA); gll16(gA1, lA + 512);
        gll16(gB0, lB); gll16(gB1, lB + 512);
        gA0 += 32; gA1 += 32; gB0 += 32; gB1 += 32;
        __syncthreads();   // compiler drains vmcnt(0) before s_barrier
        bf16x8 af[4], bfr[4];
#pragma unroll
        for (int mi = 0; mi < 4; ++mi)
            af[mi] = *(const bf16x8*)(&As[wm + mi * 16 + l16][cR]);
#pragma unroll
        for (int ni = 0; ni < 4; ++ni)
            bfr[ni] = *(const bf16x8*)(&Bs[wn + ni * 16 + l16][cR]);
#pragma unroll
        for (int mi = 0; mi < 4; ++mi)
#pragma unroll
            for (int ni = 0; ni < 4; ++ni)
                acc[mi][ni] = __builtin_amdgcn_mfma_f32_16x16x32_bf16(
                    af[mi], bfr[ni], acc[mi][ni], 0, 0, 0);
        __syncthreads();   // all ds_reads done before next tile overwrites LDS
    }

#pragma unroll
    for (int ni = 0; ni < 4; ++ni) {
        int col = n0 + wn + ni * 16 + l16;
        if (col >= Nsub) continue;
        float bv = bias[col];
#pragma unroll
        for (int mi = 0; mi < 4; ++mi)
#pragma unroll
            for (int r = 0; r < 4; ++r) {
                int row = m0 + wm + mi * 16 + lq * 4 + r;
                if (row < M) {
                    float v = acc[mi][ni][r] + bv;
                    if (act && v < 0.f) v *= 0.01f;
                    if (obf) ((bf16_t*)Cm)[(size_t)row * Nsub + col] = (bf16_t)v;
                    else     ((float*)Cm)[(size_t)row * Nsub + col] = v;
                }
            }
    }
}

// ------- fp32 GEMM (layer-1 / decoder-2): 64x64 tile, 4x4/thread, BK=16 -------
#define TM 64
#define TN 64
#define TK 16
__global__ __launch_bounds__(256) void k_gemm(
        const float* __restrict__ A, const float* __restrict__ B,
        const float* __restrict__ bias, void* __restrict__ Cm,
        int M, int Nsub, int K, int ldb, int act, int obf) {
    __shared__ float As[TK][TM];
    __shared__ float Bs[TK][TN];
    int tid = threadIdx.x;
    int tx = tid % 16, ty = tid / 16;
    int m0 = blockIdx.y * TM, n0 = blockIdx.x * TN;
    float acc[4][4] = {};
    for (int k0 = 0; k0 < K; k0 += TK) {
#pragma unroll
        for (int i = 0; i < 4; ++i) {
            int idx = tid * 4 + i;
            int m = idx >> 4, k = idx & 15;
            float v = 0.f;
            if (k0 + k < K && m0 + m < M) v = A[(size_t)(m0 + m) * K + k0 + k];
            As[k][m] = v;
        }
#pragma unroll
        for (int i = 0; i < 4; ++i) {
            int idx = tid * 4 + i;
            int k = idx >> 6, n = idx & 63;
            float v = 0.f;
            if (k0 + k < K && n0 + n < Nsub) v = B[(size_t)(k0 + k) * ldb + n0 + n];
            Bs[k][n] = v;
        }
        __syncthreads();
#pragma unroll
        for (int kk = 0; kk < TK; ++kk) {
            float4 a4 = *(const float4*)&As[kk][ty * 4];
            float4 b4 = *(const float4*)&Bs[kk][tx * 4];
            float af[4] = {a4.x, a4.y, a4.z, a4.w};
            float bf[4] = {b4.x, b4.y, b4.z, b4.w};
#pragma unroll
            for (int i = 0; i < 4; ++i)
#pragma unroll
                for (int j = 0; j < 4; ++j)
                    acc[i][j] += af[i] * bf[j];
        }
        __syncthreads();
    }
#pragma unroll
    for (int i = 0; i < 4; ++i) {
        int m = m0 + ty * 4 + i;
        if (m >= M) continue;
#pragma unroll
        for (int j = 0; j < 4; ++j) {
            int n = n0 + tx * 4 + j;
            if (n < Nsub) {
                float v = acc[i][j] + bias[n];
                if (act && v < 0.f) v *= 0.01f;
                if (obf) ((bf16_t*)Cm)[(size_t)m * Nsub + n] = (bf16_t)v;
                else     ((float*)Cm)[(size_t)m * Nsub + n] = v;
            }
        }
    }
}

__global__ void k_gemm_naive(const float* __restrict__ A, const float* __restrict__ B,
                             const float* __restrict__ bias, float* __restrict__ out,
                             int M, int N, int K, int act) {
    int idx = blockIdx.x * 256 + threadIdx.x;
    if (idx >= M * N) return;
    int m = idx / N, n = idx % N;
    float s = bias[n];
    for (int k = 0; k < K; ++k)
        s += A[(size_t)m * K + k] * B[(size_t)k * N + n];
    if (act && s < 0.f) s *= 0.01f;
    out[idx] = s;
}

// ------- attention scores: one wave per (edge, local head), bf16x4 loads -------
__global__ void k_score(const bf16_t* __restrict__ xl, const bf16_t* __restrict__ xr,
                        const float* __restrict__ att, const int* __restrict__ srcA,
                        const int* __restrict__ dstA, float* __restrict__ sc,
                        int C, int HG, int h0) {
    int wid = (blockIdx.x * 256 + threadIdx.x) >> 6;
    int lane = threadIdx.x & 63;
    if (wid >= ETOT * HG) return;
    int e = wid / HG, hl = wid % HG;
    int s = srcA[e], d = dstA[e];
    const bf16x4* pl = (const bf16x4*)(xl + ((size_t)s * HG + hl) * C);
    const bf16x4* pr = (const bf16x4*)(xr + ((size_t)d * HG + hl) * C);
    const float4* pa = (const float4*)(att + (size_t)(h0 + hl) * C);
    float acc = 0.f;
    int C4 = C >> 2;
    for (int c = lane; c < C4; c += 64) {
        bf16x4 a = pl[c], b = pr[c];
        float4 w = pa[c];
        float v;
        v = (float)a[0] + (float)b[0]; v = v > 0.f ? v : 0.2f * v; acc += v * w.x;
        v = (float)a[1] + (float)b[1]; v = v > 0.f ? v : 0.2f * v; acc += v * w.y;
        v = (float)a[2] + (float)b[2]; v = v > 0.f ? v : 0.2f * v; acc += v * w.z;
        v = (float)a[3] + (float)b[3]; v = v > 0.f ? v : 0.2f * v; acc += v * w.w;
    }
#pragma unroll
    for (int off = 32; off; off >>= 1) acc += __shfl_down(acc, off, 64);
    if (lane == 0) sc[(size_t)e * HH + h0 + hl] = acc;
}

// ---------------- softmax per (dst, head) over incoming edges -----------------
__global__ void k_softmax(const int* __restrict__ off, const int* __restrict__ csre,
                          float* __restrict__ sc, int HG, int h0) {
    int idx = blockIdx.x * 256 + threadIdx.x;
    if (idx >= NN * HG) return;
    int d = idx / HG, h = h0 + idx % HG;
    int b = off[d], en = off[d + 1];
    float m = -1e30f;
    for (int i = b; i < en; ++i) m = fmaxf(m, sc[(size_t)csre[i] * HH + h]);
    float ssum = 0.f;
    for (int i = b; i < en; ++i) ssum += expf(sc[(size_t)csre[i] * HH + h] - m);
    float inv = 1.f / ssum;
    for (int i = b; i < en; ++i) {
        size_t p = (size_t)csre[i] * HH + h;
        sc[p] = expf(sc[p] - m) * inv;
    }
}

// ------- aggregate: thread handles 4 channels, bf16x4 gathers, float4 z I/O -----
__global__ void k_aggregate(const bf16_t* __restrict__ xl, const float* __restrict__ sc,
                            const int* __restrict__ off, const int* __restrict__ csre,
                            const int* __restrict__ srcA, const float* __restrict__ bias,
                            float* __restrict__ z, int C, int HG, int h0,
                            int first, int last, int act) {
    int d = blockIdx.x;
    int c4 = blockIdx.y * 256 + threadIdx.x;
    int C4 = C >> 2;
    if (c4 >= C4) return;
    float4 acc = {0.f, 0.f, 0.f, 0.f};
    int b = off[d], en = off[d + 1];
    for (int i = b; i < en; ++i) {
        int e = csre[i];
        int s = srcA[e];
        const bf16x4* pl = (const bf16x4*)(xl + (size_t)s * HG * C) + c4;
        const float* pa = sc + (size_t)e * HH + h0;
        for (int hl = 0; hl < HG; ++hl) {
            bf16x4 vx = pl[(size_t)hl * C4];
            float w = pa[hl];
            acc.x += w * (float)vx[0];
            acc.y += w * (float)vx[1];
            acc.z += w * (float)vx[2];
            acc.w += w * (float)vx[3];
        }
    }
    float4* zp = (float4*)(z + (size_t)d * C) + c4;
    if (!first) {
        float4 prev = *zp;
        acc.x += prev.x; acc.y += prev.y; acc.z += prev.z; acc.w += prev.w;
    }
    if (last) {
        const float4 bz = *((const float4*)bias + c4);
        acc.x = acc.x * (1.f / 32.f) + bz.x;
        acc.y = acc.y * (1.f / 32.f) + bz.y;
        acc.z = acc.z * (1.f / 32.f) + bz.z;
        acc.w = acc.w * (1.f / 32.f) + bz.w;
        if (act) {
            acc.x = acc.x < 0.f ? acc.x * 0.01f : acc.x;
            acc.y = acc.y < 0.f ? acc.y * 0.01f : acc.y;
            acc.z = acc.z < 0.f ? acc.z * 0.01f : acc.z;
            acc.w = acc.w < 0.f ? acc.w * 0.01f : acc.w;
        }
    }
    *zp = acc;
}

// ---------------- host ----------------
extern "C" void kernel_launch(void* const* d_in, const int* in_sizes, int n_in,
                              void* d_out, int out_size, void* d_ws, size_t ws_size,
                              hipStream_t stream) {
    const float* x   = (const float*)d_in[0];
    const int* ei    = (const int*)d_in[1];
    const float* w1l = (const float*)d_in[2];  const float* b1l = (const float*)d_in[3];
    const float* w1r = (const float*)d_in[4];  const float* b1r = (const float*)d_in[5];
    const float* att1= (const float*)d_in[6];  const float* gb1 = (const float*)d_in[7];
    const float* w2l = (const float*)d_in[8];  const float* b2l = (const float*)d_in[9];
    const float* w2r = (const float*)d_in[10]; const float* b2r = (const float*)d_in[11];
    const float* att2= (const float*)d_in[12]; const float* gb2 = (const float*)d_in[13];
    const float* w3l = (const float*)d_in[14]; const float* b3l = (const float*)d_in[15];
    const float* w3r = (const float*)d_in[16]; const float* b3r = (const float*)d_in[17];
    const float* att3= (const float*)d_in[18]; const float* gb3 = (const float*)d_in[19];
    const float* dw1 = (const float*)d_in[20]; const float* db1 = (const float*)d_in[21];
    const float* dw2 = (const float*)d_in[22]; const float* db2 = (const float*)d_in[23];
    const float* dw3 = (const float*)d_in[24]; const float* db3 = (const float*)d_in[25];
    float* outp = (float*)d_out;

    char* p = (char*)d_ws;
    auto alloc = [&](size_t bytes) -> char* {
        char* r = p;
        p += (bytes + 255) & ~(size_t)255;
        return r;
    };
    float* sc   = (float*)alloc((size_t)ETOT * HH * 4);
    float* za   = (float*)alloc((size_t)NN * 1028 * 4);
    float* zb   = (float*)alloc((size_t)NN * 1028 * 4);
    bf16_t* Abf = (bf16_t*)alloc((size_t)NN * 1056 * 2);
    int*   ints = (int*)  alloc((size_t)(2 * NN + 16) * 4);
    int* cnt  = ints;
    int* cur  = ints + NN;
    int* flag = ints + 2 * NN;
    int* offp = (int*)alloc((size_t)(NN + 1) * 4);
    int* csre = (int*)alloc((size_t)ETOT * 4);
    int* srcA = (int*)alloc((size_t)ETOT * 4);
    int* dstA = (int*)alloc((size_t)ETOT * 4);
    size_t used = (size_t)(p - (char*)d_ws);
    size_t remain = (ws_size > used) ? (ws_size - used) : 0;
    char* chunk = p;

    k_zero_int<<<dim3((2 * NN + 16 + 255) / 256), dim3(256), 0, stream>>>(ints, 2 * NN + 16);
    k_detect<<<dim3((EE + 255) / 256), dim3(256), 0, stream>>>(ei, flag);
    k_edge_prep<<<dim3((ETOT + 255) / 256), dim3(256), 0, stream>>>(ei, flag, srcA, dstA, cnt);
    k_scan<<<dim3(1), dim3(NN), 0, stream>>>(cnt, offp);
    k_fill<<<dim3((ETOT + 255) / 256), dim3(256), 0, stream>>>(dstA, offp, cur, csre);

    struct Layer {
        const float* in; int cin; int C;
        const float *wl, *bl, *wr, *br, *att, *gb;
        float* zout; int act;
    };
    Layer L[3] = {
        { x,    4, 128,  w1l, b1l, w1r, b1r, att1, gb1, za, 1 },
        { za, 128, 512,  w2l, b2l, w2r, b2r, att2, gb2, zb, 1 },
        { zb, 512, 1028, w3l, b3l, w3r, b3r, att3, gb3, za, 0 },
    };
    auto al = [](size_t n) { return (n + 127) & ~(size_t)127; };

    for (int li = 0; li < 3; ++li) {
        int C = L[li].C, K = L[li].cin;
        bool mfma = (K >= 128);
        int Kp = (K + 31) & ~31;
        // per-head chunk bytes: xl + xr bf16 (+ Bt for mfma path)
        size_t perHG = 2ull * NN * C * 2 + (mfma ? (size_t)C * Kp * 2 : 0);
        int HG = 32;
        // 1MB slack: gload_lds staging may over-read up to one 128-row panel
        while (HG > 1 && (size_t)HG * perHG + (1u << 20) > remain) HG >>= 1;
        int nchunk = HH / HG;
        bf16_t* xlc = (bf16_t*)chunk;
        bf16_t* xrc = xlc + al((size_t)NN * HG * C);
        bf16_t* Bt  = xrc + al((size_t)NN * HG * C);

        if (mfma)
            k_convA<<<dim3((NN * Kp + 255) / 256), dim3(256), 0, stream>>>(L[li].in, Abf, NN, K, Kp);

        for (int hg = 0; hg < nchunk; ++hg) {
            int h0 = hg * HG;
            int colOff = h0 * C;
            int Nsub = HG * C;
            if (mfma) {
                dim3 gc((Nsub + 31) / 32, Kp / 32);
                dim3 gg((Nsub + 127) / 128, NN / 128);
                k_convB<<<gc, dim3(256), 0, stream>>>(L[li].wl + colOff, Bt, K, Nsub, HH * C, Kp);
                k_gemm_bf16<<<gg, dim3(256), 0, stream>>>(Abf, Bt, L[li].bl + colOff, xlc, NN, Nsub, Kp, 0, 1);
                k_convB<<<gc, dim3(256), 0, stream>>>(L[li].wr + colOff, Bt, K, Nsub, HH * C, Kp);
                k_gemm_bf16<<<gg, dim3(256), 0, stream>>>(Abf, Bt, L[li].br + colOff, xrc, NN, Nsub, Kp, 0, 1);
            } else {
                dim3 gg((Nsub + TN - 1) / TN, (NN + TM - 1) / TM);
                k_gemm<<<gg, dim3(256), 0, stream>>>(L[li].in, L[li].wl + colOff, L[li].bl + colOff,
                                                     xlc, NN, Nsub, K, HH * C, 0, 1);
                k_gemm<<<gg, dim3(256), 0, stream>>>(L[li].in, L[li].wr + colOff, L[li].br + colOff,
                                                     xrc, NN, Nsub, K, HH * C, 0, 1);
            }
            int waves = ETOT * HG;
            k_score<<<dim3((waves * 64 + 255) / 256), dim3(256), 0, stream>>>(
                xlc, xrc, L[li].att, srcA, dstA, sc, C, HG, h0);
            k_softmax<<<dim3((NN * HG + 255) / 256), dim3(256), 0, stream>>>(offp, csre, sc, HG, h0);
            int C4 = C >> 2;
            dim3 ga(NN, (C4 + 255) / 256);
            k_aggregate<<<ga, dim3(256), 0, stream>>>(xlc, sc, offp, csre, srcA, L[li].gb,
                                                      L[li].zout, C, HG, h0,
                                                      hg == 0, hg == nchunk - 1, L[li].act);
        }
    }

    // ---- decoder ----
    {
        int K = 1028, Kp = 1056, Nsub = 512;
        bf16_t* Bt = (bf16_t*)chunk;
        k_convA<<<dim3((NN * Kp + 255) / 256), dim3(256), 0, stream>>>(za, Abf, NN, K, Kp);
        k_convB<<<dim3(Nsub / 32, Kp / 32), dim3(256), 0, stream>>>(dw1, Bt, K, Nsub, Nsub, Kp);
        k_gemm_bf16<<<dim3(Nsub / 128, NN / 128), dim3(256), 0, stream>>>(Abf, Bt, db1, zb, NN, Nsub, Kp, 1, 0);
    }
    k_gemm<<<dim3(128 / TN, NN / TM), dim3(256), 0, stream>>>(zb, dw2, db2, za, NN, 128, 512, 128, 1, 0);
    k_gemm_naive<<<dim3((NN * 2 + 255) / 256), dim3(256), 0, stream>>>(za, dw3, db3, outp, NN, 2, 128, 0);
}

// Round 2
// 896.209 us; speedup vs baseline: 1.1571x; 1.1110x over previous
//
#include <hip/hip_runtime.h>
#include <cstdint>
#include <cstddef>

#define NN 1024
#define EE 2048
#define ETOT 3072
#define HH 32

typedef __bf16 bf16_t;
typedef __attribute__((ext_vector_type(8))) __bf16 bf16x8;
typedef __attribute__((ext_vector_type(4))) __bf16 bf16x4;
typedef __attribute__((ext_vector_type(2))) __bf16 bf16x2;
typedef __attribute__((ext_vector_type(4))) float f32x4;

typedef const __attribute__((address_space(1))) void gvoid_t;
typedef __attribute__((address_space(3))) void lvoid_t;

// async global->LDS, 16B per lane. LDS dest = wave-uniform base + lane*16.
__device__ __forceinline__ void gll16(const void* g, void* l) {
    __builtin_amdgcn_global_load_lds((gvoid_t*)g, (lvoid_t*)l, 16, 0, 0);
}

// ---------------- utility ----------------
__global__ void k_zero_int(int* p, int n) {
    int i = blockIdx.x * 256 + threadIdx.x;
    if (i < n) p[i] = 0;
}

__global__ void k_detect(const int* ei, int* flag) {
    int i = blockIdx.x * 256 + threadIdx.x;
    int idx = 2 * i + 1;
    if (idx < 2 * EE && ei[idx] != 0) atomicOr(flag, 1);
}

__global__ void k_edge_prep(const int* ei, const int* flag, int* srcA, int* dstA, int* cnt) {
    int e = blockIdx.x * 256 + threadIdx.x;
    if (e >= ETOT) return;
    int s, d;
    if (e < EE) {
        if (*flag) { s = ei[e]; d = ei[EE + e]; }
        else       { s = ei[2 * e]; d = ei[2 * (EE + e)]; }
        s &= (NN - 1); d &= (NN - 1);
    } else {
        s = d = e - EE;
    }
    srcA[e] = s; dstA[e] = d;
    atomicAdd(&cnt[d], 1);
}

__global__ void k_scan(const int* cnt, int* off) {
    __shared__ int sh[NN];
    int t = threadIdx.x;
    sh[t] = cnt[t];
    __syncthreads();
    for (int o = 1; o < NN; o <<= 1) {
        int v = (t >= o) ? sh[t - o] : 0;
        __syncthreads();
        sh[t] += v;
        __syncthreads();
    }
    off[t + 1] = sh[t];
    if (t == 0) off[0] = 0;
}

__global__ void k_fill(const int* dstA, const int* off, int* cur, int* csre) {
    int e = blockIdx.x * 256 + threadIdx.x;
    if (e >= ETOT) return;
    int d = dstA[e];
    int p = atomicAdd(&cur[d], 1);
    csre[off[d] + p] = e;
}

// ---------------- fp32 -> bf16 converts ----------------
__global__ void k_convA(const float* __restrict__ A, bf16_t* __restrict__ Ab,
                        int M, int K, int Kp) {
    int idx = blockIdx.x * 256 + threadIdx.x;
    if (idx >= M * Kp) return;
    int m = idx / Kp, k = idx % Kp;
    Ab[idx] = (k < K) ? (bf16_t)A[(size_t)m * K + k] : (bf16_t)0.f;
}

// transpose-convert: B[K][ldb] fp32 -> Bt[Nsub][Kp] bf16. bf16x2 writes (4B/lane).
__global__ void k_convB(const float* __restrict__ B, bf16_t* __restrict__ Bt,
                        int K, int Nsub, int ldb, int Kp) {
    __shared__ float sh[32][33];
    int kt = blockIdx.y * 32, nt = blockIdx.x * 32;
    int tx = threadIdx.x & 31, ty = threadIdx.x >> 5;
#pragma unroll
    for (int i = 0; i < 4; ++i) {
        int k = kt + ty + i * 8, n = nt + tx;
        sh[ty + i * 8][tx] = (k < K && n < Nsub) ? B[(size_t)k * ldb + n] : 0.f;
    }
    __syncthreads();
    int k2 = (threadIdx.x & 15) * 2;   // even k within tile
    int nl = threadIdx.x >> 4;         // 0..15
#pragma unroll
    for (int i = 0; i < 2; ++i) {
        int n = nt + nl + i * 16;
        if (n < Nsub) {
            bf16x2 v;
            v[0] = (bf16_t)sh[k2][nl + i * 16];
            v[1] = (bf16_t)sh[k2 + 1][nl + i * 16];
            *(bf16x2*)(&Bt[(size_t)n * Kp + kt + k2]) = v;
        }
    }
}

// ---------------- bf16 MFMA GEMM: 2-phase double-buffered pipeline ----------------
// C[M x Nsub] = Ab[M x Kp] @ Bt[Nsub x Kp]^T + bias; output fp32 or bf16 (obf).
// T3-minimum schedule: issue next tile's global_load_lds into the alternate LDS
// buffer BEFORE ds_read+MFMA of the current tile; one vmcnt(0)+barrier per tile
// (via __syncthreads) so load latency hides under compute.
// LDS layout: SH[buf][A(4096 bf16) | B(4096 bf16)]; 16B-slot XOR swizzle on the
// GLOBAL source, undone on the fragment read (rule #21). XCD-aware remap kept.
// Epilogue (obf path): re-layout C tile through LDS (slot-XOR swizzled) and
// store coalesced bf16x8 rows -> full-line HBM writes.
__global__ __launch_bounds__(256) void k_gemm_bf16(
        const bf16_t* __restrict__ Ab, const bf16_t* __restrict__ Bt,
        const float* __restrict__ bias, void* __restrict__ Cm,
        int M, int Nsub, int Kp, int act, int obf) {
    __shared__ __align__(16) bf16_t SH[16384];   // 32KB: 2 bufs x (A 8KB + B 8KB)
    int tid = threadIdx.x;
    int wave = tid >> 6, lane = tid & 63;
    int wm = (wave & 1) * 64, wn = (wave >> 1) * 64;
    int l16 = lane & 15, lq = lane >> 4;

    // XCD-aware remap (y fastest within each chunk): blocks sharing one
    // B-panel become consecutive in dispatch order -> same XCD L2.
    int nx = gridDim.x, ny = gridDim.y;
    int bx = blockIdx.x, by = blockIdx.y;
    int total = nx * ny;
    if ((total & 7) == 0) {
        int j = bx + nx * by;
        int w = (j & 7) * (total >> 3) + (j >> 3);
        bx = w / ny;
        by = w % ny;
    }
    int m0 = by * 128, n0 = bx * 128;

    // staging: 8KB per tile = 512 x 16B units; unit u -> row r = u>>2, slot u&3.
    // global source slot = lds slot ^ ((r>>1)&3)  (involution; undone on read)
    int u0 = wave * 128 + lane;
    int u1 = u0 + 64;
    int r0 = u0 >> 2, s0 = u0 & 3;
    int r1 = u1 >> 2, s1 = u1 & 3;
    int c0 = ((s0 ^ ((r0 >> 1) & 3)) << 3);   // bf16 elements within row
    int c1 = ((s1 ^ ((r1 >> 1) & 3)) << 3);
    const bf16_t* gA0 = Ab + (size_t)(m0 + r0) * Kp + c0;
    const bf16_t* gA1 = Ab + (size_t)(m0 + r1) * Kp + c1;
    const bf16_t* gB0 = Bt + (size_t)(n0 + r0) * Kp + c0;
    const bf16_t* gB1 = Bt + (size_t)(n0 + r1) * Kp + c1;

    // fragment-read swizzle (same involution)
    int cR = ((lq ^ ((l16 >> 1) & 3)) << 3);

    f32x4 acc[4][4] = {};
    int nt = Kp >> 5;

    // prologue: stage tile 0 into buf 0
    {
        bf16_t* d = SH + wave * 1024;
        gll16(gA0, d); gll16(gA1, d + 512);
        gll16(gB0, d + 4096); gll16(gB1, d + 4096 + 512);
        gA0 += 32; gA1 += 32; gB0 += 32; gB1 += 32;
    }
    __syncthreads();

    for (int t = 0; t < nt; ++t) {
        int cur = t & 1;
        // issue next tile's loads into the alternate buffer (hidden under compute)
        if (t + 1 < nt) {
            bf16_t* d = SH + (cur ^ 1) * 8192 + wave * 1024;
            gll16(gA0, d); gll16(gA1, d + 512);
            gll16(gB0, d + 4096); gll16(gB1, d + 4096 + 512);
            gA0 += 32; gA1 += 32; gB0 += 32; gB1 += 32;
        }
        __builtin_amdgcn_sched_barrier(0);   // pin stage-issue before ds_reads
        const bf16_t* rb = SH + cur * 8192;
        bf16x8 af[4], bfr[4];
#pragma unroll
        for (int mi = 0; mi < 4; ++mi)
            af[mi] = *(const bf16x8*)(rb + (wm + mi * 16 + l16) * 32 + cR);
#pragma unroll
        for (int ni = 0; ni < 4; ++ni)
            bfr[ni] = *(const bf16x8*)(rb + 4096 + (wn + ni * 16 + l16) * 32 + cR);
#pragma unroll
        for (int mi = 0; mi < 4; ++mi)
#pragma unroll
            for (int ni = 0; ni < 4; ++ni)
                acc[mi][ni] = __builtin_amdgcn_mfma_f32_16x16x32_bf16(
                    af[mi], bfr[ni], acc[mi][ni], 0, 0, 0);
        __syncthreads();   // vmcnt(0)+lgkmcnt(0)+barrier: next tile ready, LDS free
    }

    if (obf) {
        // ---- LDS re-layout epilogue: coalesced bf16x8 C stores ----
        // write acc -> SH with 16B-slot XOR swizzle (slot ^= row&7)
#pragma unroll
        for (int ni = 0; ni < 4; ++ni) {
            int cl = wn + ni * 16 + l16;
            float bv = bias[n0 + cl];
#pragma unroll
            for (int mi = 0; mi < 4; ++mi)
#pragma unroll
                for (int r = 0; r < 4; ++r) {
                    int rl = wm + mi * 16 + lq * 4 + r;
                    float v = acc[mi][ni][r] + bv;
                    if (act && v < 0.f) v *= 0.01f;
                    int slot = ((cl >> 3) ^ (rl & 7)) & 15;
                    SH[rl * 128 + slot * 8 + (cl & 7)] = (bf16_t)v;
                }
        }
        __syncthreads();
        // read back sequentially (conflict-free) and store 16B/lane
        bf16_t* Cb = (bf16_t*)Cm;
#pragma unroll
        for (int i = 0; i < 8; ++i) {
            int j = i * 2048 + tid * 8;       // bf16 index into SH
            int rl = j >> 7;
            int p = (j >> 3) & 15;
            int cl = ((p ^ (rl & 7)) & 15) * 8;
            bf16x8 v = *(const bf16x8*)(SH + rl * 128 + p * 8);
            int row = m0 + rl, col = n0 + cl;
            if (row < M) {
                if (col + 7 < Nsub) {
                    *(bf16x8*)(Cb + (size_t)row * Nsub + col) = v;
                } else {
#pragma unroll
                    for (int e = 0; e < 8; ++e)
                        if (col + e < Nsub) Cb[(size_t)row * Nsub + col + e] = v[e];
                }
            }
        }
    } else {
        // fp32 output path (decoder-1): direct stores
#pragma unroll
        for (int ni = 0; ni < 4; ++ni) {
            int col = n0 + wn + ni * 16 + l16;
            if (col >= Nsub) continue;
            float bv = bias[col];
#pragma unroll
            for (int mi = 0; mi < 4; ++mi)
#pragma unroll
                for (int r = 0; r < 4; ++r) {
                    int row = m0 + wm + mi * 16 + lq * 4 + r;
                    if (row < M) {
                        float v = acc[mi][ni][r] + bv;
                        if (act && v < 0.f) v *= 0.01f;
                        ((float*)Cm)[(size_t)row * Nsub + col] = v;
                    }
                }
        }
    }
}

// ------- fp32 GEMM (layer-1 / decoder-2): 64x64 tile, 4x4/thread, BK=16 -------
#define TM 64
#define TN 64
#define TK 16
__global__ __launch_bounds__(256) void k_gemm(
        const float* __restrict__ A, const float* __restrict__ B,
        const float* __restrict__ bias, void* __restrict__ Cm,
        int M, int Nsub, int K, int ldb, int act, int obf) {
    __shared__ float As[TK][TM];
    __shared__ float Bs[TK][TN];
    int tid = threadIdx.x;
    int tx = tid % 16, ty = tid / 16;
    int m0 = blockIdx.y * TM, n0 = blockIdx.x * TN;
    float acc[4][4] = {};
    for (int k0 = 0; k0 < K; k0 += TK) {
#pragma unroll
        for (int i = 0; i < 4; ++i) {
            int idx = tid * 4 + i;
            int m = idx >> 4, k = idx & 15;
            float v = 0.f;
            if (k0 + k < K && m0 + m < M) v = A[(size_t)(m0 + m) * K + k0 + k];
            As[k][m] = v;
        }
#pragma unroll
        for (int i = 0; i < 4; ++i) {
            int idx = tid * 4 + i;
            int k = idx >> 6, n = idx & 63;
            float v = 0.f;
            if (k0 + k < K && n0 + n < Nsub) v = B[(size_t)(k0 + k) * ldb + n0 + n];
            Bs[k][n] = v;
        }
        __syncthreads();
#pragma unroll
        for (int kk = 0; kk < TK; ++kk) {
            float4 a4 = *(const float4*)&As[kk][ty * 4];
            float4 b4 = *(const float4*)&Bs[kk][tx * 4];
            float af[4] = {a4.x, a4.y, a4.z, a4.w};
            float bf[4] = {b4.x, b4.y, b4.z, b4.w};
#pragma unroll
            for (int i = 0; i < 4; ++i)
#pragma unroll
                for (int j = 0; j < 4; ++j)
                    acc[i][j] += af[i] * bf[j];
        }
        __syncthreads();
    }
#pragma unroll
    for (int i = 0; i < 4; ++i) {
        int m = m0 + ty * 4 + i;
        if (m >= M) continue;
#pragma unroll
        for (int j = 0; j < 4; ++j) {
            int n = n0 + tx * 4 + j;
            if (n < Nsub) {
                float v = acc[i][j] + bias[n];
                if (act && v < 0.f) v *= 0.01f;
                if (obf) ((bf16_t*)Cm)[(size_t)m * Nsub + n] = (bf16_t)v;
                else     ((float*)Cm)[(size_t)m * Nsub + n] = v;
            }
        }
    }
}

__global__ void k_gemm_naive(const float* __restrict__ A, const float* __restrict__ B,
                             const float* __restrict__ bias, float* __restrict__ out,
                             int M, int N, int K, int act) {
    int idx = blockIdx.x * 256 + threadIdx.x;
    if (idx >= M * N) return;
    int m = idx / N, n = idx % N;
    float s = bias[n];
    for (int k = 0; k < K; ++k)
        s += A[(size_t)m * K + k] * B[(size_t)k * N + n];
    if (act && s < 0.f) s *= 0.01f;
    out[idx] = s;
}

// ------- attention scores: one wave per (edge, local head), bf16x4 loads -------
__global__ void k_score(const bf16_t* __restrict__ xl, const bf16_t* __restrict__ xr,
                        const float* __restrict__ att, const int* __restrict__ srcA,
                        const int* __restrict__ dstA, float* __restrict__ sc,
                        int C, int HG, int h0) {
    int wid = (blockIdx.x * 256 + threadIdx.x) >> 6;
    int lane = threadIdx.x & 63;
    if (wid >= ETOT * HG) return;
    int e = wid / HG, hl = wid % HG;
    int s = srcA[e], d = dstA[e];
    const bf16x4* pl = (const bf16x4*)(xl + ((size_t)s * HG + hl) * C);
    const bf16x4* pr = (const bf16x4*)(xr + ((size_t)d * HG + hl) * C);
    const float4* pa = (const float4*)(att + (size_t)(h0 + hl) * C);
    float acc = 0.f;
    int C4 = C >> 2;
    for (int c = lane; c < C4; c += 64) {
        bf16x4 a = pl[c], b = pr[c];
        float4 w = pa[c];
        float v;
        v = (float)a[0] + (float)b[0]; v = v > 0.f ? v : 0.2f * v; acc += v * w.x;
        v = (float)a[1] + (float)b[1]; v = v > 0.f ? v : 0.2f * v; acc += v * w.y;
        v = (float)a[2] + (float)b[2]; v = v > 0.f ? v : 0.2f * v; acc += v * w.z;
        v = (float)a[3] + (float)b[3]; v = v > 0.f ? v : 0.2f * v; acc += v * w.w;
    }
#pragma unroll
    for (int off = 32; off; off >>= 1) acc += __shfl_down(acc, off, 64);
    if (lane == 0) sc[(size_t)e * HH + h0 + hl] = acc;
}

// ---------------- softmax per (dst, head) over incoming edges -----------------
__global__ void k_softmax(const int* __restrict__ off, const int* __restrict__ csre,
                          float* __restrict__ sc, int HG, int h0) {
    int idx = blockIdx.x * 256 + threadIdx.x;
    if (idx >= NN * HG) return;
    int d = idx / HG, h = h0 + idx % HG;
    int b = off[d], en = off[d + 1];
    float m = -1e30f;
    for (int i = b; i < en; ++i) m = fmaxf(m, sc[(size_t)csre[i] * HH + h]);
    float ssum = 0.f;
    for (int i = b; i < en; ++i) ssum += expf(sc[(size_t)csre[i] * HH + h] - m);
    float inv = 1.f / ssum;
    for (int i = b; i < en; ++i) {
        size_t p = (size_t)csre[i] * HH + h;
        sc[p] = expf(sc[p] - m) * inv;
    }
}

// ------- aggregate: thread handles 4 channels, bf16x4 gathers, float4 z I/O -----
__global__ void k_aggregate(const bf16_t* __restrict__ xl, const float* __restrict__ sc,
                            const int* __restrict__ off, const int* __restrict__ csre,
                            const int* __restrict__ srcA, const float* __restrict__ bias,
                            float* __restrict__ z, int C, int HG, int h0,
                            int first, int last, int act) {
    int d = blockIdx.x;
    int c4 = blockIdx.y * 256 + threadIdx.x;
    int C4 = C >> 2;
    if (c4 >= C4) return;
    float4 acc = {0.f, 0.f, 0.f, 0.f};
    int b = off[d], en = off[d + 1];
    for (int i = b; i < en; ++i) {
        int e = csre[i];
        int s = srcA[e];
        const bf16x4* pl = (const bf16x4*)(xl + (size_t)s * HG * C) + c4;
        const float* pa = sc + (size_t)e * HH + h0;
        for (int hl = 0; hl < HG; ++hl) {
            bf16x4 vx = pl[(size_t)hl * C4];
            float w = pa[hl];
            acc.x += w * (float)vx[0];
            acc.y += w * (float)vx[1];
            acc.z += w * (float)vx[2];
            acc.w += w * (float)vx[3];
        }
    }
    float4* zp = (float4*)(z + (size_t)d * C) + c4;
    if (!first) {
        float4 prev = *zp;
        acc.x += prev.x; acc.y += prev.y; acc.z += prev.z; acc.w += prev.w;
    }
    if (last) {
        const float4 bz = *((const float4*)bias + c4);
        acc.x = acc.x * (1.f / 32.f) + bz.x;
        acc.y = acc.y * (1.f / 32.f) + bz.y;
        acc.z = acc.z * (1.f / 32.f) + bz.z;
        acc.w = acc.w * (1.f / 32.f) + bz.w;
        if (act) {
            acc.x = acc.x < 0.f ? acc.x * 0.01f : acc.x;
            acc.y = acc.y < 0.f ? acc.y * 0.01f : acc.y;
            acc.z = acc.z < 0.f ? acc.z * 0.01f : acc.z;
            acc.w = acc.w < 0.f ? acc.w * 0.01f : acc.w;
        }
    }
    *zp = acc;
}

// ---------------- host ----------------
extern "C" void kernel_launch(void* const* d_in, const int* in_sizes, int n_in,
                              void* d_out, int out_size, void* d_ws, size_t ws_size,
                              hipStream_t stream) {
    const float* x   = (const float*)d_in[0];
    const int* ei    = (const int*)d_in[1];
    const float* w1l = (const float*)d_in[2];  const float* b1l = (const float*)d_in[3];
    const float* w1r = (const float*)d_in[4];  const float* b1r = (const float*)d_in[5];
    const float* att1= (const float*)d_in[6];  const float* gb1 = (const float*)d_in[7];
    const float* w2l = (const float*)d_in[8];  const float* b2l = (const float*)d_in[9];
    const float* w2r = (const float*)d_in[10]; const float* b2r = (const float*)d_in[11];
    const float* att2= (const float*)d_in[12]; const float* gb2 = (const float*)d_in[13];
    const float* w3l = (const float*)d_in[14]; const float* b3l = (const float*)d_in[15];
    const float* w3r = (const float*)d_in[16]; const float* b3r = (const float*)d_in[17];
    const float* att3= (const float*)d_in[18]; const float* gb3 = (const float*)d_in[19];
    const float* dw1 = (const float*)d_in[20]; const float* db1 = (const float*)d_in[21];
    const float* dw2 = (const float*)d_in[22]; const float* db2 = (const float*)d_in[23];
    const float* dw3 = (const float*)d_in[24]; const float* db3 = (const float*)d_in[25];
    float* outp = (float*)d_out;

    char* p = (char*)d_ws;
    auto alloc = [&](size_t bytes) -> char* {
        char* r = p;
        p += (bytes + 255) & ~(size_t)255;
        return r;
    };
    float* sc   = (float*)alloc((size_t)ETOT * HH * 4);
    float* za   = (float*)alloc((size_t)NN * 1028 * 4);
    float* zb   = (float*)alloc((size_t)NN * 1028 * 4);
    bf16_t* Abf = (bf16_t*)alloc((size_t)NN * 1056 * 2);
    int*   ints = (int*)  alloc((size_t)(2 * NN + 16) * 4);
    int* cnt  = ints;
    int* cur  = ints + NN;
    int* flag = ints + 2 * NN;
    int* offp = (int*)alloc((size_t)(NN + 1) * 4);
    int* csre = (int*)alloc((size_t)ETOT * 4);
    int* srcA = (int*)alloc((size_t)ETOT * 4);
    int* dstA = (int*)alloc((size_t)ETOT * 4);
    size_t used = (size_t)(p - (char*)d_ws);
    size_t remain = (ws_size > used) ? (ws_size - used) : 0;
    char* chunk = p;

    k_zero_int<<<dim3((2 * NN + 16 + 255) / 256), dim3(256), 0, stream>>>(ints, 2 * NN + 16);
    k_detect<<<dim3((EE + 255) / 256), dim3(256), 0, stream>>>(ei, flag);
    k_edge_prep<<<dim3((ETOT + 255) / 256), dim3(256), 0, stream>>>(ei, flag, srcA, dstA, cnt);
    k_scan<<<dim3(1), dim3(NN), 0, stream>>>(cnt, offp);
    k_fill<<<dim3((ETOT + 255) / 256), dim3(256), 0, stream>>>(dstA, offp, cur, csre);

    struct Layer {
        const float* in; int cin; int C;
        const float *wl, *bl, *wr, *br, *att, *gb;
        float* zout; int act;
    };
    Layer L[3] = {
        { x,    4, 128,  w1l, b1l, w1r, b1r, att1, gb1, za, 1 },
        { za, 128, 512,  w2l, b2l, w2r, b2r, att2, gb2, zb, 1 },
        { zb, 512, 1028, w3l, b3l, w3r, b3r, att3, gb3, za, 0 },
    };
    auto al = [](size_t n) { return (n + 127) & ~(size_t)127; };

    for (int li = 0; li < 3; ++li) {
        int C = L[li].C, K = L[li].cin;
        bool mfma = (K >= 128);
        int Kp = (K + 31) & ~31;
        // per-head chunk bytes: xl + xr bf16 (+ Bt for mfma path)
        size_t perHG = 2ull * NN * C * 2 + (mfma ? (size_t)C * Kp * 2 : 0);
        int HG = 32;
        // 1MB slack: gload_lds staging may over-read up to one 128-row panel
        while (HG > 1 && (size_t)HG * perHG + (1u << 20) > remain) HG >>= 1;
        int nchunk = HH / HG;
        bf16_t* xlc = (bf16_t*)chunk;
        bf16_t* xrc = xlc + al((size_t)NN * HG * C);
        bf16_t* Bt  = xrc + al((size_t)NN * HG * C);

        if (mfma)
            k_convA<<<dim3((NN * Kp + 255) / 256), dim3(256), 0, stream>>>(L[li].in, Abf, NN, K, Kp);

        for (int hg = 0; hg < nchunk; ++hg) {
            int h0 = hg * HG;
            int colOff = h0 * C;
            int Nsub = HG * C;
            if (mfma) {
                dim3 gc((Nsub + 31) / 32, Kp / 32);
                dim3 gg((Nsub + 127) / 128, NN / 128);
                k_convB<<<gc, dim3(256), 0, stream>>>(L[li].wl + colOff, Bt, K, Nsub, HH * C, Kp);
                k_gemm_bf16<<<gg, dim3(256), 0, stream>>>(Abf, Bt, L[li].bl + colOff, xlc, NN, Nsub, Kp, 0, 1);
                k_convB<<<gc, dim3(256), 0, stream>>>(L[li].wr + colOff, Bt, K, Nsub, HH * C, Kp);
                k_gemm_bf16<<<gg, dim3(256), 0, stream>>>(Abf, Bt, L[li].br + colOff, xrc, NN, Nsub, Kp, 0, 1);
            } else {
                dim3 gg((Nsub + TN - 1) / TN, (NN + TM - 1) / TM);
                k_gemm<<<gg, dim3(256), 0, stream>>>(L[li].in, L[li].wl + colOff, L[li].bl + colOff,
                                                     xlc, NN, Nsub, K, HH * C, 0, 1);
                k_gemm<<<gg, dim3(256), 0, stream>>>(L[li].in, L[li].wr + colOff, L[li].br + colOff,
                                                     xrc, NN, Nsub, K, HH * C, 0, 1);
            }
            int waves = ETOT * HG;
            k_score<<<dim3((waves * 64 + 255) / 256), dim3(256), 0, stream>>>(
                xlc, xrc, L[li].att, srcA, dstA, sc, C, HG, h0);
            k_softmax<<<dim3((NN * HG + 255) / 256), dim3(256), 0, stream>>>(offp, csre, sc, HG, h0);
            int C4 = C >> 2;
            dim3 ga(NN, (C4 + 255) / 256);
            k_aggregate<<<ga, dim3(256), 0, stream>>>(xlc, sc, offp, csre, srcA, L[li].gb,
                                                      L[li].zout, C, HG, h0,
                                                      hg == 0, hg == nchunk - 1, L[li].act);
        }
    }

    // ---- decoder ----
    {
        int K = 1028, Kp = 1056, Nsub = 512;
        bf16_t* Bt = (bf16_t*)chunk;
        k_convA<<<dim3((NN * Kp + 255) / 256), dim3(256), 0, stream>>>(za, Abf, NN, K, Kp);
        k_convB<<<dim3(Nsub / 32, Kp / 32), dim3(256), 0, stream>>>(dw1, Bt, K, Nsub, Nsub, Kp);
        k_gemm_bf16<<<dim3(Nsub / 128, NN / 128), dim3(256), 0, stream>>>(Abf, Bt, db1, zb, NN, Nsub, Kp, 1, 0);
    }
    k_gemm<<<dim3(128 / TN, NN / TM), dim3(256), 0, stream>>>(zb, dw2, db2, za, NN, 128, 512, 128, 1, 0);
    k_gemm_naive<<<dim3((NN * 2 + 255) / 256), dim3(256), 0, stream>>>(za, dw3, db3, outp, NN, 2, 128, 0);
}

// Round 3
// 748.519 us; speedup vs baseline: 1.3855x; 1.1973x over previous
//
#include <hip/hip_runtime.h>
#include <cstdint>
#include <cstddef>

#define NN 1024
#define EE 2048
#define ETOT 3072
#define HH 32

typedef __bf16 bf16_t;
typedef __attribute__((ext_vector_type(8))) __bf16 bf16x8;
typedef __attribute__((ext_vector_type(4))) __bf16 bf16x4;
typedef __attribute__((ext_vector_type(2))) __bf16 bf16x2;
typedef __attribute__((ext_vector_type(4))) float f32x4;

typedef const __attribute__((address_space(1))) void gvoid_t;
typedef __attribute__((address_space(3))) void lvoid_t;

// async global->LDS, 16B per lane. LDS dest = wave-uniform base + lane*16.
__device__ __forceinline__ void gll16(const void* g, void* l) {
    __builtin_amdgcn_global_load_lds((gvoid_t*)g, (lvoid_t*)l, 16, 0, 0);
}

// ---------------- utility ----------------
__global__ void k_zero_int(int* p, int n) {
    int i = blockIdx.x * 256 + threadIdx.x;
    if (i < n) p[i] = 0;
}

__global__ void k_detect(const int* ei, int* flag) {
    int i = blockIdx.x * 256 + threadIdx.x;
    int idx = 2 * i + 1;
    if (idx < 2 * EE && ei[idx] != 0) atomicOr(flag, 1);
}

__global__ void k_edge_prep(const int* ei, const int* flag, int* srcA, int* dstA, int* cnt) {
    int e = blockIdx.x * 256 + threadIdx.x;
    if (e >= ETOT) return;
    int s, d;
    if (e < EE) {
        if (*flag) { s = ei[e]; d = ei[EE + e]; }
        else       { s = ei[2 * e]; d = ei[2 * (EE + e)]; }
        s &= (NN - 1); d &= (NN - 1);
    } else {
        s = d = e - EE;
    }
    srcA[e] = s; dstA[e] = d;
    atomicAdd(&cnt[d], 1);
}

__global__ void k_scan(const int* cnt, int* off) {
    __shared__ int sh[NN];
    int t = threadIdx.x;
    sh[t] = cnt[t];
    __syncthreads();
    for (int o = 1; o < NN; o <<= 1) {
        int v = (t >= o) ? sh[t - o] : 0;
        __syncthreads();
        sh[t] += v;
        __syncthreads();
    }
    off[t + 1] = sh[t];
    if (t == 0) off[0] = 0;
}

__global__ void k_fill(const int* dstA, const int* off, int* cur, int* csre) {
    int e = blockIdx.x * 256 + threadIdx.x;
    if (e >= ETOT) return;
    int d = dstA[e];
    int p = atomicAdd(&cur[d], 1);
    csre[off[d] + p] = e;
}

// ---------------- fp32 -> bf16 converts ----------------
__global__ void k_convA(const float* __restrict__ A, bf16_t* __restrict__ Ab,
                        int M, int K, int Kp) {
    int idx = blockIdx.x * 256 + threadIdx.x;
    if (idx >= M * Kp) return;
    int m = idx / Kp, k = idx % Kp;
    Ab[idx] = (k < K) ? (bf16_t)A[(size_t)m * K + k] : (bf16_t)0.f;
}

// transpose-convert: B[K][ldb] fp32 -> Bt[Nsub][Kp] bf16. bf16x2 writes (4B/lane).
__global__ void k_convB(const float* __restrict__ B, bf16_t* __restrict__ Bt,
                        int K, int Nsub, int ldb, int Kp) {
    __shared__ float sh[32][33];
    int kt = blockIdx.y * 32, nt = blockIdx.x * 32;
    int tx = threadIdx.x & 31, ty = threadIdx.x >> 5;
#pragma unroll
    for (int i = 0; i < 4; ++i) {
        int k = kt + ty + i * 8, n = nt + tx;
        sh[ty + i * 8][tx] = (k < K && n < Nsub) ? B[(size_t)k * ldb + n] : 0.f;
    }
    __syncthreads();
    int k2 = (threadIdx.x & 15) * 2;   // even k within tile
    int nl = threadIdx.x >> 4;         // 0..15
#pragma unroll
    for (int i = 0; i < 2; ++i) {
        int n = nt + nl + i * 16;
        if (n < Nsub) {
            bf16x2 v;
            v[0] = (bf16_t)sh[k2][nl + i * 16];
            v[1] = (bf16_t)sh[k2 + 1][nl + i * 16];
            *(bf16x2*)(&Bt[(size_t)n * Kp + kt + k2]) = v;
        }
    }
}

// ---------------- bf16 MFMA GEMM: 2-phase double-buffered pipeline ----------------
__global__ __launch_bounds__(256) void k_gemm_bf16(
        const bf16_t* __restrict__ Ab, const bf16_t* __restrict__ Bt,
        const float* __restrict__ bias, void* __restrict__ Cm,
        int M, int Nsub, int Kp, int act, int obf) {
    __shared__ __align__(16) bf16_t SH[16384];   // 32KB: 2 bufs x (A 8KB + B 8KB)
    int tid = threadIdx.x;
    int wave = tid >> 6, lane = tid & 63;
    int wm = (wave & 1) * 64, wn = (wave >> 1) * 64;
    int l16 = lane & 15, lq = lane >> 4;

    // XCD-aware remap (y fastest within each chunk)
    int nx = gridDim.x, ny = gridDim.y;
    int bx = blockIdx.x, by = blockIdx.y;
    int total = nx * ny;
    if ((total & 7) == 0) {
        int j = bx + nx * by;
        int w = (j & 7) * (total >> 3) + (j >> 3);
        bx = w / ny;
        by = w % ny;
    }
    int m0 = by * 128, n0 = bx * 128;

    // staging: 8KB per tile = 512 x 16B units; unit u -> row r = u>>2, slot u&3.
    // global source slot = lds slot ^ ((r>>1)&3)  (involution; undone on read)
    int u0 = wave * 128 + lane;
    int u1 = u0 + 64;
    int r0 = u0 >> 2, s0 = u0 & 3;
    int r1 = u1 >> 2, s1 = u1 & 3;
    int c0 = ((s0 ^ ((r0 >> 1) & 3)) << 3);   // bf16 elements within row
    int c1 = ((s1 ^ ((r1 >> 1) & 3)) << 3);
    const bf16_t* gA0 = Ab + (size_t)(m0 + r0) * Kp + c0;
    const bf16_t* gA1 = Ab + (size_t)(m0 + r1) * Kp + c1;
    const bf16_t* gB0 = Bt + (size_t)(n0 + r0) * Kp + c0;
    const bf16_t* gB1 = Bt + (size_t)(n0 + r1) * Kp + c1;

    // fragment-read swizzle (same involution)
    int cR = ((lq ^ ((l16 >> 1) & 3)) << 3);

    f32x4 acc[4][4] = {};
    int nt = Kp >> 5;

    // prologue: stage tile 0 into buf 0
    {
        bf16_t* d = SH + wave * 1024;
        gll16(gA0, d); gll16(gA1, d + 512);
        gll16(gB0, d + 4096); gll16(gB1, d + 4096 + 512);
        gA0 += 32; gA1 += 32; gB0 += 32; gB1 += 32;
    }
    __syncthreads();

    for (int t = 0; t < nt; ++t) {
        int cur = t & 1;
        // issue next tile's loads into the alternate buffer (hidden under compute)
        if (t + 1 < nt) {
            bf16_t* d = SH + (cur ^ 1) * 8192 + wave * 1024;
            gll16(gA0, d); gll16(gA1, d + 512);
            gll16(gB0, d + 4096); gll16(gB1, d + 4096 + 512);
            gA0 += 32; gA1 += 32; gB0 += 32; gB1 += 32;
        }
        __builtin_amdgcn_sched_barrier(0);   // pin stage-issue before ds_reads
        const bf16_t* rb = SH + cur * 8192;
        bf16x8 af[4], bfr[4];
#pragma unroll
        for (int mi = 0; mi < 4; ++mi)
            af[mi] = *(const bf16x8*)(rb + (wm + mi * 16 + l16) * 32 + cR);
#pragma unroll
        for (int ni = 0; ni < 4; ++ni)
            bfr[ni] = *(const bf16x8*)(rb + 4096 + (wn + ni * 16 + l16) * 32 + cR);
#pragma unroll
        for (int mi = 0; mi < 4; ++mi)
#pragma unroll
            for (int ni = 0; ni < 4; ++ni)
                acc[mi][ni] = __builtin_amdgcn_mfma_f32_16x16x32_bf16(
                    af[mi], bfr[ni], acc[mi][ni], 0, 0, 0);
        __syncthreads();   // vmcnt(0)+lgkmcnt(0)+barrier: next tile ready, LDS free
    }

    if (obf) {
        // ---- LDS re-layout epilogue: coalesced bf16x8 C stores ----
#pragma unroll
        for (int ni = 0; ni < 4; ++ni) {
            int cl = wn + ni * 16 + l16;
            float bv = bias[n0 + cl];
#pragma unroll
            for (int mi = 0; mi < 4; ++mi)
#pragma unroll
                for (int r = 0; r < 4; ++r) {
                    int rl = wm + mi * 16 + lq * 4 + r;
                    float v = acc[mi][ni][r] + bv;
                    if (act && v < 0.f) v *= 0.01f;
                    int slot = ((cl >> 3) ^ (rl & 7)) & 15;
                    SH[rl * 128 + slot * 8 + (cl & 7)] = (bf16_t)v;
                }
        }
        __syncthreads();
        bf16_t* Cb = (bf16_t*)Cm;
#pragma unroll
        for (int i = 0; i < 8; ++i) {
            int j = i * 2048 + tid * 8;       // bf16 index into SH
            int rl = j >> 7;
            int p = (j >> 3) & 15;
            int cl = ((p ^ (rl & 7)) & 15) * 8;
            bf16x8 v = *(const bf16x8*)(SH + rl * 128 + p * 8);
            int row = m0 + rl, col = n0 + cl;
            if (row < M) {
                if (col + 7 < Nsub) {
                    *(bf16x8*)(Cb + (size_t)row * Nsub + col) = v;
                } else {
#pragma unroll
                    for (int e = 0; e < 8; ++e)
                        if (col + e < Nsub) Cb[(size_t)row * Nsub + col + e] = v[e];
                }
            }
        }
    } else {
        // fp32 output path (decoder-1): direct stores
#pragma unroll
        for (int ni = 0; ni < 4; ++ni) {
            int col = n0 + wn + ni * 16 + l16;
            if (col >= Nsub) continue;
            float bv = bias[col];
#pragma unroll
            for (int mi = 0; mi < 4; ++mi)
#pragma unroll
                for (int r = 0; r < 4; ++r) {
                    int row = m0 + wm + mi * 16 + lq * 4 + r;
                    if (row < M) {
                        float v = acc[mi][ni][r] + bv;
                        if (act && v < 0.f) v *= 0.01f;
                        ((float*)Cm)[(size_t)row * Nsub + col] = v;
                    }
                }
        }
    }
}

// ------- fp32 GEMM (layer-1 / decoder-2): 64x64 tile, 4x4/thread, BK=16 -------
#define TM 64
#define TN 64
#define TK 16
__global__ __launch_bounds__(256) void k_gemm(
        const float* __restrict__ A, const float* __restrict__ B,
        const float* __restrict__ bias, void* __restrict__ Cm,
        int M, int Nsub, int K, int ldb, int act, int obf) {
    __shared__ float As[TK][TM];
    __shared__ float Bs[TK][TN];
    int tid = threadIdx.x;
    int tx = tid % 16, ty = tid / 16;
    int m0 = blockIdx.y * TM, n0 = blockIdx.x * TN;
    float acc[4][4] = {};
    for (int k0 = 0; k0 < K; k0 += TK) {
#pragma unroll
        for (int i = 0; i < 4; ++i) {
            int idx = tid * 4 + i;
            int m = idx >> 4, k = idx & 15;
            float v = 0.f;
            if (k0 + k < K && m0 + m < M) v = A[(size_t)(m0 + m) * K + k0 + k];
            As[k][m] = v;
        }
#pragma unroll
        for (int i = 0; i < 4; ++i) {
            int idx = tid * 4 + i;
            int k = idx >> 6, n = idx & 63;
            float v = 0.f;
            if (k0 + k < K && n0 + n < Nsub) v = B[(size_t)(k0 + k) * ldb + n0 + n];
            Bs[k][n] = v;
        }
        __syncthreads();
#pragma unroll
        for (int kk = 0; kk < TK; ++kk) {
            float4 a4 = *(const float4*)&As[kk][ty * 4];
            float4 b4 = *(const float4*)&Bs[kk][tx * 4];
            float af[4] = {a4.x, a4.y, a4.z, a4.w};
            float bf[4] = {b4.x, b4.y, b4.z, b4.w};
#pragma unroll
            for (int i = 0; i < 4; ++i)
#pragma unroll
                for (int j = 0; j < 4; ++j)
                    acc[i][j] += af[i] * bf[j];
        }
        __syncthreads();
    }
#pragma unroll
    for (int i = 0; i < 4; ++i) {
        int m = m0 + ty * 4 + i;
        if (m >= M) continue;
#pragma unroll
        for (int j = 0; j < 4; ++j) {
            int n = n0 + tx * 4 + j;
            if (n < Nsub) {
                float v = acc[i][j] + bias[n];
                if (act && v < 0.f) v *= 0.01f;
                if (obf) ((bf16_t*)Cm)[(size_t)m * Nsub + n] = (bf16_t)v;
                else     ((float*)Cm)[(size_t)m * Nsub + n] = v;
            }
        }
    }
}

__global__ void k_gemm_naive(const float* __restrict__ A, const float* __restrict__ B,
                             const float* __restrict__ bias, float* __restrict__ out,
                             int M, int N, int K, int act) {
    int idx = blockIdx.x * 256 + threadIdx.x;
    if (idx >= M * N) return;
    int m = idx / N, n = idx % N;
    float s = bias[n];
    for (int k = 0; k < K; ++k)
        s += A[(size_t)m * K + k] * B[(size_t)k * N + n];
    if (act && s < 0.f) s *= 0.01f;
    out[idx] = s;
}

// ------- attention scores: one wave per (edge, local head), bf16x4 loads -------
__global__ void k_score(const bf16_t* __restrict__ xl, const bf16_t* __restrict__ xr,
                        const float* __restrict__ att, const int* __restrict__ srcA,
                        const int* __restrict__ dstA, float* __restrict__ sc,
                        int C, int HG, int h0) {
    int wid = (blockIdx.x * 256 + threadIdx.x) >> 6;
    int lane = threadIdx.x & 63;
    if (wid >= ETOT * HG) return;
    int e = wid / HG, hl = wid % HG;
    int s = srcA[e], d = dstA[e];
    const bf16x4* pl = (const bf16x4*)(xl + ((size_t)s * HG + hl) * C);
    const bf16x4* pr = (const bf16x4*)(xr + ((size_t)d * HG + hl) * C);
    const float4* pa = (const float4*)(att + (size_t)(h0 + hl) * C);
    float acc = 0.f;
    int C4 = C >> 2;
    for (int c = lane; c < C4; c += 64) {
        bf16x4 a = pl[c], b = pr[c];
        float4 w = pa[c];
        float v;
        v = (float)a[0] + (float)b[0]; v = v > 0.f ? v : 0.2f * v; acc += v * w.x;
        v = (float)a[1] + (float)b[1]; v = v > 0.f ? v : 0.2f * v; acc += v * w.y;
        v = (float)a[2] + (float)b[2]; v = v > 0.f ? v : 0.2f * v; acc += v * w.z;
        v = (float)a[3] + (float)b[3]; v = v > 0.f ? v : 0.2f * v; acc += v * w.w;
    }
#pragma unroll
    for (int off = 32; off; off >>= 1) acc += __shfl_down(acc, off, 64);
    if (lane == 0) sc[(size_t)e * HH + h0 + hl] = acc;
}

// ---------------- softmax per (dst, head) over incoming edges -----------------
__global__ void k_softmax(const int* __restrict__ off, const int* __restrict__ csre,
                          float* __restrict__ sc, int HG, int h0) {
    int idx = blockIdx.x * 256 + threadIdx.x;
    if (idx >= NN * HG) return;
    int d = idx / HG, h = h0 + idx % HG;
    int b = off[d], en = off[d + 1];
    float m = -1e30f;
    for (int i = b; i < en; ++i) m = fmaxf(m, sc[(size_t)csre[i] * HH + h]);
    float ssum = 0.f;
    for (int i = b; i < en; ++i) ssum += expf(sc[(size_t)csre[i] * HH + h] - m);
    float inv = 1.f / ssum;
    for (int i = b; i < en; ++i) {
        size_t p = (size_t)csre[i] * HH + h;
        sc[p] = expf(sc[p] - m) * inv;
    }
}

// ------- aggregate: block = (dst, c4-tile), thread = (hl, c4i) ---------------
// Heads parallelized INTO the block (NC = 256/HG channels-of-4 per block);
// per-thread work is ~3 edge iterations (latency hidden by block count);
// hl-partials reduced via LDS tree; first/last chunk-accumulation unchanged.
__global__ __launch_bounds__(256) void k_aggregate(
        const bf16_t* __restrict__ xl, const float* __restrict__ sc,
        const int* __restrict__ off, const int* __restrict__ csre,
        const int* __restrict__ srcA, const float* __restrict__ bias,
        float* __restrict__ z, int C, int HG, int h0, int lgNC,
        int first, int last, int act) {
    __shared__ float4 sh[256];
    int d = blockIdx.x;
    int NC = 1 << lgNC;
    int c4i = threadIdx.x & (NC - 1);
    int hl = threadIdx.x >> lgNC;
    int c4 = blockIdx.y * NC + c4i;
    int C4 = C >> 2;
    bool active = (c4 < C4);
    float4 acc = {0.f, 0.f, 0.f, 0.f};
    int b = off[d], en = off[d + 1];
    for (int i = b; i < en; ++i) {
        int e = csre[i];
        int s = srcA[e];
        float w = sc[(size_t)e * HH + h0 + hl];
        if (active) {
            bf16x4 vx = *((const bf16x4*)(xl + ((size_t)s * HG + hl) * C) + c4);
            acc.x += w * (float)vx[0];
            acc.y += w * (float)vx[1];
            acc.z += w * (float)vx[2];
            acc.w += w * (float)vx[3];
        }
    }
    sh[threadIdx.x] = acc;
    __syncthreads();
    for (int s = HG >> 1; s >= 1; s >>= 1) {
        if (hl < s) {
            float4 o = sh[threadIdx.x + (s << lgNC)];
            float4 m = sh[threadIdx.x];
            m.x += o.x; m.y += o.y; m.z += o.z; m.w += o.w;
            sh[threadIdx.x] = m;
        }
        __syncthreads();
    }
    if (hl == 0 && active) {
        acc = sh[threadIdx.x];
        float4* zp = (float4*)(z + (size_t)d * C) + c4;
        if (!first) {
            float4 prev = *zp;
            acc.x += prev.x; acc.y += prev.y; acc.z += prev.z; acc.w += prev.w;
        }
        if (last) {
            const float4 bz = *((const float4*)bias + c4);
            acc.x = acc.x * (1.f / 32.f) + bz.x;
            acc.y = acc.y * (1.f / 32.f) + bz.y;
            acc.z = acc.z * (1.f / 32.f) + bz.z;
            acc.w = acc.w * (1.f / 32.f) + bz.w;
            if (act) {
                acc.x = acc.x < 0.f ? acc.x * 0.01f : acc.x;
                acc.y = acc.y < 0.f ? acc.y * 0.01f : acc.y;
                acc.z = acc.z < 0.f ? acc.z * 0.01f : acc.z;
                acc.w = acc.w < 0.f ? acc.w * 0.01f : acc.w;
            }
        }
        *zp = acc;
    }
}

// ---------------- host ----------------
extern "C" void kernel_launch(void* const* d_in, const int* in_sizes, int n_in,
                              void* d_out, int out_size, void* d_ws, size_t ws_size,
                              hipStream_t stream) {
    const float* x   = (const float*)d_in[0];
    const int* ei    = (const int*)d_in[1];
    const float* w1l = (const float*)d_in[2];  const float* b1l = (const float*)d_in[3];
    const float* w1r = (const float*)d_in[4];  const float* b1r = (const float*)d_in[5];
    const float* att1= (const float*)d_in[6];  const float* gb1 = (const float*)d_in[7];
    const float* w2l = (const float*)d_in[8];  const float* b2l = (const float*)d_in[9];
    const float* w2r = (const float*)d_in[10]; const float* b2r = (const float*)d_in[11];
    const float* att2= (const float*)d_in[12]; const float* gb2 = (const float*)d_in[13];
    const float* w3l = (const float*)d_in[14]; const float* b3l = (const float*)d_in[15];
    const float* w3r = (const float*)d_in[16]; const float* b3r = (const float*)d_in[17];
    const float* att3= (const float*)d_in[18]; const float* gb3 = (const float*)d_in[19];
    const float* dw1 = (const float*)d_in[20]; const float* db1 = (const float*)d_in[21];
    const float* dw2 = (const float*)d_in[22]; const float* db2 = (const float*)d_in[23];
    const float* dw3 = (const float*)d_in[24]; const float* db3 = (const float*)d_in[25];
    float* outp = (float*)d_out;

    char* p = (char*)d_ws;
    auto alloc = [&](size_t bytes) -> char* {
        char* r = p;
        p += (bytes + 255) & ~(size_t)255;
        return r;
    };
    float* sc   = (float*)alloc((size_t)ETOT * HH * 4);
    float* za   = (float*)alloc((size_t)NN * 1028 * 4);
    float* zb   = (float*)alloc((size_t)NN * 1028 * 4);
    bf16_t* Abf = (bf16_t*)alloc((size_t)NN * 1056 * 2);
    int*   ints = (int*)  alloc((size_t)(2 * NN + 16) * 4);
    int* cnt  = ints;
    int* cur  = ints + NN;
    int* flag = ints + 2 * NN;
    int* offp = (int*)alloc((size_t)(NN + 1) * 4);
    int* csre = (int*)alloc((size_t)ETOT * 4);
    int* srcA = (int*)alloc((size_t)ETOT * 4);
    int* dstA = (int*)alloc((size_t)ETOT * 4);
    size_t used = (size_t)(p - (char*)d_ws);
    size_t remain = (ws_size > used) ? (ws_size - used) : 0;
    char* chunk = p;

    k_zero_int<<<dim3((2 * NN + 16 + 255) / 256), dim3(256), 0, stream>>>(ints, 2 * NN + 16);
    k_detect<<<dim3((EE + 255) / 256), dim3(256), 0, stream>>>(ei, flag);
    k_edge_prep<<<dim3((ETOT + 255) / 256), dim3(256), 0, stream>>>(ei, flag, srcA, dstA, cnt);
    k_scan<<<dim3(1), dim3(NN), 0, stream>>>(cnt, offp);
    k_fill<<<dim3((ETOT + 255) / 256), dim3(256), 0, stream>>>(dstA, offp, cur, csre);

    struct Layer {
        const float* in; int cin; int C;
        const float *wl, *bl, *wr, *br, *att, *gb;
        float* zout; int act;
    };
    Layer L[3] = {
        { x,    4, 128,  w1l, b1l, w1r, b1r, att1, gb1, za, 1 },
        { za, 128, 512,  w2l, b2l, w2r, b2r, att2, gb2, zb, 1 },
        { zb, 512, 1028, w3l, b3l, w3r, b3r, att3, gb3, za, 0 },
    };
    auto al = [](size_t n) { return (n + 127) & ~(size_t)127; };

    for (int li = 0; li < 3; ++li) {
        int C = L[li].C, K = L[li].cin;
        bool mfma = (K >= 128);
        int Kp = (K + 31) & ~31;
        // per-head chunk bytes: xl + xr bf16 (+ Bt for mfma path)
        size_t perHG = 2ull * NN * C * 2 + (mfma ? (size_t)C * Kp * 2 : 0);
        int HG = 32;
        // 1MB slack: gload_lds staging may over-read up to one 128-row panel
        while (HG > 1 && (size_t)HG * perHG + (1u << 20) > remain) HG >>= 1;
        int nchunk = HH / HG;
        int lgNC = 0;
        while ((1 << lgNC) * HG < 256) ++lgNC;   // NC = 256/HG
        int NC = 1 << lgNC;
        bf16_t* xlc = (bf16_t*)chunk;
        bf16_t* xrc = xlc + al((size_t)NN * HG * C);
        bf16_t* Bt  = xrc + al((size_t)NN * HG * C);

        if (mfma)
            k_convA<<<dim3((NN * Kp + 255) / 256), dim3(256), 0, stream>>>(L[li].in, Abf, NN, K, Kp);

        for (int hg = 0; hg < nchunk; ++hg) {
            int h0 = hg * HG;
            int colOff = h0 * C;
            int Nsub = HG * C;
            if (mfma) {
                dim3 gc((Nsub + 31) / 32, Kp / 32);
                dim3 gg((Nsub + 127) / 128, NN / 128);
                k_convB<<<gc, dim3(256), 0, stream>>>(L[li].wl + colOff, Bt, K, Nsub, HH * C, Kp);
                k_gemm_bf16<<<gg, dim3(256), 0, stream>>>(Abf, Bt, L[li].bl + colOff, xlc, NN, Nsub, Kp, 0, 1);
                k_convB<<<gc, dim3(256), 0, stream>>>(L[li].wr + colOff, Bt, K, Nsub, HH * C, Kp);
                k_gemm_bf16<<<gg, dim3(256), 0, stream>>>(Abf, Bt, L[li].br + colOff, xrc, NN, Nsub, Kp, 0, 1);
            } else {
                dim3 gg((Nsub + TN - 1) / TN, (NN + TM - 1) / TM);
                k_gemm<<<gg, dim3(256), 0, stream>>>(L[li].in, L[li].wl + colOff, L[li].bl + colOff,
                                                     xlc, NN, Nsub, K, HH * C, 0, 1);
                k_gemm<<<gg, dim3(256), 0, stream>>>(L[li].in, L[li].wr + colOff, L[li].br + colOff,
                                                     xrc, NN, Nsub, K, HH * C, 0, 1);
            }
            int waves = ETOT * HG;
            k_score<<<dim3((waves * 64 + 255) / 256), dim3(256), 0, stream>>>(
                xlc, xrc, L[li].att, srcA, dstA, sc, C, HG, h0);
            k_softmax<<<dim3((NN * HG + 255) / 256), dim3(256), 0, stream>>>(offp, csre, sc, HG, h0);
            int C4 = C >> 2;
            dim3 ga(NN, (C4 + NC - 1) / NC);
            k_aggregate<<<ga, dim3(256), 0, stream>>>(xlc, sc, offp, csre, srcA, L[li].gb,
                                                      L[li].zout, C, HG, h0, lgNC,
                                                      hg == 0, hg == nchunk - 1, L[li].act);
        }
    }

    // ---- decoder ----
    {
        int K = 1028, Kp = 1056, Nsub = 512;
        bf16_t* Bt = (bf16_t*)chunk;
        k_convA<<<dim3((NN * Kp + 255) / 256), dim3(256), 0, stream>>>(za, Abf, NN, K, Kp);
        k_convB<<<dim3(Nsub / 32, Kp / 32), dim3(256), 0, stream>>>(dw1, Bt, K, Nsub, Nsub, Kp);
        k_gemm_bf16<<<dim3(Nsub / 128, NN / 128), dim3(256), 0, stream>>>(Abf, Bt, db1, zb, NN, Nsub, Kp, 1, 0);
    }
    k_gemm<<<dim3(128 / TN, NN / TM), dim3(256), 0, stream>>>(zb, dw2, db2, za, NN, 128, 512, 128, 1, 0);
    k_gemm_naive<<<dim3((NN * 2 + 255) / 256), dim3(256), 0, stream>>>(za, dw3, db3, outp, NN, 2, 128, 0);
}

// Round 4
// 729.773 us; speedup vs baseline: 1.4210x; 1.0257x over previous
//
#include <hip/hip_runtime.h>
#include <cstdint>
#include <cstddef>

#define NN 1024
#define EE 2048
#define ETOT 3072
#define HH 32

typedef __bf16 bf16_t;
typedef __attribute__((ext_vector_type(8))) __bf16 bf16x8;
typedef __attribute__((ext_vector_type(4))) __bf16 bf16x4;
typedef __attribute__((ext_vector_type(2))) __bf16 bf16x2;
typedef __attribute__((ext_vector_type(4))) float f32x4;

typedef const __attribute__((address_space(1))) void gvoid_t;
typedef __attribute__((address_space(3))) void lvoid_t;

// async global->LDS, 16B per lane. LDS dest = wave-uniform base + lane*16.
__device__ __forceinline__ void gll16(const void* g, void* l) {
    __builtin_amdgcn_global_load_lds((gvoid_t*)g, (lvoid_t*)l, 16, 0, 0);
}

// ---------------- utility ----------------
__global__ void k_zero_int(int* p, int n) {
    int i = blockIdx.x * 256 + threadIdx.x;
    if (i < n) p[i] = 0;
}

__global__ void k_detect(const int* ei, int* flag) {
    int i = blockIdx.x * 256 + threadIdx.x;
    int idx = 2 * i + 1;
    if (idx < 2 * EE && ei[idx] != 0) atomicOr(flag, 1);
}

__global__ void k_edge_prep(const int* ei, const int* flag, int* srcA, int* dstA, int* cnt) {
    int e = blockIdx.x * 256 + threadIdx.x;
    if (e >= ETOT) return;
    int s, d;
    if (e < EE) {
        if (*flag) { s = ei[e]; d = ei[EE + e]; }
        else       { s = ei[2 * e]; d = ei[2 * (EE + e)]; }
        s &= (NN - 1); d &= (NN - 1);
    } else {
        s = d = e - EE;
    }
    srcA[e] = s; dstA[e] = d;
    atomicAdd(&cnt[d], 1);
}

__global__ void k_scan(const int* cnt, int* off) {
    __shared__ int sh[NN];
    int t = threadIdx.x;
    sh[t] = cnt[t];
    __syncthreads();
    for (int o = 1; o < NN; o <<= 1) {
        int v = (t >= o) ? sh[t - o] : 0;
        __syncthreads();
        sh[t] += v;
        __syncthreads();
    }
    off[t + 1] = sh[t];
    if (t == 0) off[0] = 0;
}

__global__ void k_fill(const int* dstA, const int* off, int* cur, int* csre) {
    int e = blockIdx.x * 256 + threadIdx.x;
    if (e >= ETOT) return;
    int d = dstA[e];
    int p = atomicAdd(&cur[d], 1);
    csre[off[d] + p] = e;
}

// ---------------- fp32 -> bf16 converts ----------------
__global__ void k_convA(const float* __restrict__ A, bf16_t* __restrict__ Ab,
                        int M, int K, int Kp) {
    int idx = blockIdx.x * 256 + threadIdx.x;
    if (idx >= M * Kp) return;
    int m = idx / Kp, k = idx % Kp;
    Ab[idx] = (k < K) ? (bf16_t)A[(size_t)m * K + k] : (bf16_t)0.f;
}

// transpose-convert: B[K][ldb] fp32 -> Bt[Nsub][Kp] bf16. bf16x4 writes (8B/lane),
// lanes 0-7 cover one contiguous 64B row segment -> coalesced.
__global__ void k_convB(const float* __restrict__ B, bf16_t* __restrict__ Bt,
                        int K, int Nsub, int ldb, int Kp) {
    __shared__ float sh[32][33];
    int kt = blockIdx.y * 32, nt = blockIdx.x * 32;
    int tx = threadIdx.x & 31, ty = threadIdx.x >> 5;
#pragma unroll
    for (int i = 0; i < 4; ++i) {
        int k = kt + ty + i * 8, n = nt + tx;
        sh[ty + i * 8][tx] = (k < K && n < Nsub) ? B[(size_t)k * ldb + n] : 0.f;
    }
    __syncthreads();
    int kq = (threadIdx.x & 7) * 4;    // k group of 4
    int nl = threadIdx.x >> 3;         // 0..31
    int n = nt + nl;
    if (n < Nsub) {
        bf16x4 v;
        v[0] = (bf16_t)sh[kq][nl];
        v[1] = (bf16_t)sh[kq + 1][nl];
        v[2] = (bf16_t)sh[kq + 2][nl];
        v[3] = (bf16_t)sh[kq + 3][nl];
        *(bf16x4*)(&Bt[(size_t)n * Kp + kt + kq]) = v;
    }
}

// ------- bf16 MFMA GEMM: 3-buffer depth-2 pipeline, counted vmcnt (T4) -------
// C[M x Nsub] = Ab[M x Kp] @ Bt[Nsub x Kp]^T + bias; output fp32 or bf16 (obf).
// Per iter: waitcnt(vmcnt(4)) -> s_barrier -> stage(t+2) -> ds_read(t) -> MFMA.
// vmcnt never drains to 0 mid-loop; tile t's loads have ~2 iterations to land.
// Race-freedom: barrier at iter t guarantees (a) all waves' tile-t loads done
// (each waited own vmcnt(4) pre-barrier), (b) all waves' t-1 ds_reads retired
// (their lgkmcnt wait precedes their t-1 MFMAs, which precede the barrier).
// stage(t+2) overwrites buf[(t-1)%3] -> safe after the barrier.
__global__ __launch_bounds__(256) void k_gemm_bf16(
        const bf16_t* __restrict__ Ab, const bf16_t* __restrict__ Bt,
        const float* __restrict__ bias, void* __restrict__ Cm,
        int M, int Nsub, int Kp, int act, int obf) {
    __shared__ __align__(16) bf16_t SH[24576];   // 48KB: 3 bufs x (A 8KB + B 8KB)
    int tid = threadIdx.x;
    int wave = tid >> 6, lane = tid & 63;
    int wm = (wave & 1) * 64, wn = (wave >> 1) * 64;
    int l16 = lane & 15, lq = lane >> 4;

    // XCD-aware remap (y fastest within each chunk)
    int nx = gridDim.x, ny = gridDim.y;
    int bx = blockIdx.x, by = blockIdx.y;
    int total = nx * ny;
    if ((total & 7) == 0) {
        int j = bx + nx * by;
        int w = (j & 7) * (total >> 3) + (j >> 3);
        bx = w / ny;
        by = w % ny;
    }
    int m0 = by * 128, n0 = bx * 128;

    // staging: 8KB per tile = 512 x 16B units; unit u -> row r = u>>2, slot u&3.
    // global source slot = lds slot ^ ((r>>1)&3)  (involution; undone on read)
    int u0 = wave * 128 + lane;
    int u1 = u0 + 64;
    int r0 = u0 >> 2, s0 = u0 & 3;
    int r1 = u1 >> 2, s1 = u1 & 3;
    int c0 = ((s0 ^ ((r0 >> 1) & 3)) << 3);   // bf16 elements within row
    int c1 = ((s1 ^ ((r1 >> 1) & 3)) << 3);
    const bf16_t* gA0 = Ab + (size_t)(m0 + r0) * Kp + c0;
    const bf16_t* gA1 = Ab + (size_t)(m0 + r1) * Kp + c1;
    const bf16_t* gB0 = Bt + (size_t)(n0 + r0) * Kp + c0;
    const bf16_t* gB1 = Bt + (size_t)(n0 + r1) * Kp + c1;

    // fragment-read swizzle (same involution)
    int cR = ((lq ^ ((l16 >> 1) & 3)) << 3);

    f32x4 acc[4][4] = {};
    int nt = Kp >> 5;

    // prologue: stage tiles 0,1 into bufs 0,1
#pragma unroll
    for (int pt = 0; pt < 2; ++pt) {
        bf16_t* d = SH + pt * 8192 + wave * 1024;
        gll16(gA0, d); gll16(gA1, d + 512);
        gll16(gB0, d + 4096); gll16(gB1, d + 4096 + 512);
        gA0 += 32; gA1 += 32; gB0 += 32; gB1 += 32;
    }

    int bc = 0, bn = 2;   // current read buf, next stage buf
    for (int t = 0; t < nt; ++t) {
        if (t + 1 < nt)
            asm volatile("s_waitcnt vmcnt(4) lgkmcnt(0)" ::: "memory");
        else
            asm volatile("s_waitcnt vmcnt(0) lgkmcnt(0)" ::: "memory");
        asm volatile("s_barrier" ::: "memory");
        __builtin_amdgcn_sched_barrier(0);
        if (t + 2 < nt) {
            bf16_t* d = SH + bn * 8192 + wave * 1024;
            gll16(gA0, d); gll16(gA1, d + 512);
            gll16(gB0, d + 4096); gll16(gB1, d + 4096 + 512);
            gA0 += 32; gA1 += 32; gB0 += 32; gB1 += 32;
        }
        const bf16_t* rb = SH + bc * 8192;
        bf16x8 af[4], bfr[4];
#pragma unroll
        for (int mi = 0; mi < 4; ++mi)
            af[mi] = *(const bf16x8*)(rb + (wm + mi * 16 + l16) * 32 + cR);
#pragma unroll
        for (int ni = 0; ni < 4; ++ni)
            bfr[ni] = *(const bf16x8*)(rb + 4096 + (wn + ni * 16 + l16) * 32 + cR);
#pragma unroll
        for (int mi = 0; mi < 4; ++mi)
#pragma unroll
            for (int ni = 0; ni < 4; ++ni)
                acc[mi][ni] = __builtin_amdgcn_mfma_f32_16x16x32_bf16(
                    af[mi], bfr[ni], acc[mi][ni], 0, 0, 0);
        bc = (bc == 2) ? 0 : bc + 1;
        bn = (bn == 2) ? 0 : bn + 1;
    }
    // all waves done with LDS before epilogue reuses it
    asm volatile("s_waitcnt lgkmcnt(0)" ::: "memory");
    asm volatile("s_barrier" ::: "memory");
    __builtin_amdgcn_sched_barrier(0);

    if (obf) {
        // ---- LDS re-layout epilogue: coalesced bf16x8 C stores ----
#pragma unroll
        for (int ni = 0; ni < 4; ++ni) {
            int cl = wn + ni * 16 + l16;
            float bv = bias[n0 + cl];
#pragma unroll
            for (int mi = 0; mi < 4; ++mi)
#pragma unroll
                for (int r = 0; r < 4; ++r) {
                    int rl = wm + mi * 16 + lq * 4 + r;
                    float v = acc[mi][ni][r] + bv;
                    if (act && v < 0.f) v *= 0.01f;
                    int slot = ((cl >> 3) ^ (rl & 7)) & 15;
                    SH[rl * 128 + slot * 8 + (cl & 7)] = (bf16_t)v;
                }
        }
        __syncthreads();
        bf16_t* Cb = (bf16_t*)Cm;
#pragma unroll
        for (int i = 0; i < 8; ++i) {
            int j = i * 2048 + tid * 8;       // bf16 index into SH
            int rl = j >> 7;
            int p = (j >> 3) & 15;
            int cl = ((p ^ (rl & 7)) & 15) * 8;
            bf16x8 v = *(const bf16x8*)(SH + rl * 128 + p * 8);
            int row = m0 + rl, col = n0 + cl;
            if (row < M) {
                if (col + 7 < Nsub) {
                    *(bf16x8*)(Cb + (size_t)row * Nsub + col) = v;
                } else {
#pragma unroll
                    for (int e = 0; e < 8; ++e)
                        if (col + e < Nsub) Cb[(size_t)row * Nsub + col + e] = v[e];
                }
            }
        }
    } else {
        // fp32 output path (decoder-1): direct stores
#pragma unroll
        for (int ni = 0; ni < 4; ++ni) {
            int col = n0 + wn + ni * 16 + l16;
            if (col >= Nsub) continue;
            float bv = bias[col];
#pragma unroll
            for (int mi = 0; mi < 4; ++mi)
#pragma unroll
                for (int r = 0; r < 4; ++r) {
                    int row = m0 + wm + mi * 16 + lq * 4 + r;
                    if (row < M) {
                        float v = acc[mi][ni][r] + bv;
                        if (act && v < 0.f) v *= 0.01f;
                        ((float*)Cm)[(size_t)row * Nsub + col] = v;
                    }
                }
        }
    }
}

// ------- fp32 GEMM (layer-1 / decoder-2): 64x64 tile, 4x4/thread, BK=16 -------
#define TM 64
#define TN 64
#define TK 16
__global__ __launch_bounds__(256) void k_gemm(
        const float* __restrict__ A, const float* __restrict__ B,
        const float* __restrict__ bias, void* __restrict__ Cm,
        int M, int Nsub, int K, int ldb, int act, int obf) {
    __shared__ float As[TK][TM];
    __shared__ float Bs[TK][TN];
    int tid = threadIdx.x;
    int tx = tid % 16, ty = tid / 16;
    int m0 = blockIdx.y * TM, n0 = blockIdx.x * TN;
    float acc[4][4] = {};
    for (int k0 = 0; k0 < K; k0 += TK) {
#pragma unroll
        for (int i = 0; i < 4; ++i) {
            int idx = tid * 4 + i;
            int m = idx >> 4, k = idx & 15;
            float v = 0.f;
            if (k0 + k < K && m0 + m < M) v = A[(size_t)(m0 + m) * K + k0 + k];
            As[k][m] = v;
        }
#pragma unroll
        for (int i = 0; i < 4; ++i) {
            int idx = tid * 4 + i;
            int k = idx >> 6, n = idx & 63;
            float v = 0.f;
            if (k0 + k < K && n0 + n < Nsub) v = B[(size_t)(k0 + k) * ldb + n0 + n];
            Bs[k][n] = v;
        }
        __syncthreads();
#pragma unroll
        for (int kk = 0; kk < TK; ++kk) {
            float4 a4 = *(const float4*)&As[kk][ty * 4];
            float4 b4 = *(const float4*)&Bs[kk][tx * 4];
            float af[4] = {a4.x, a4.y, a4.z, a4.w};
            float bf[4] = {b4.x, b4.y, b4.z, b4.w};
#pragma unroll
            for (int i = 0; i < 4; ++i)
#pragma unroll
                for (int j = 0; j < 4; ++j)
                    acc[i][j] += af[i] * bf[j];
        }
        __syncthreads();
    }
#pragma unroll
    for (int i = 0; i < 4; ++i) {
        int m = m0 + ty * 4 + i;
        if (m >= M) continue;
#pragma unroll
        for (int j = 0; j < 4; ++j) {
            int n = n0 + tx * 4 + j;
            if (n < Nsub) {
                float v = acc[i][j] + bias[n];
                if (act && v < 0.f) v *= 0.01f;
                if (obf) ((bf16_t*)Cm)[(size_t)m * Nsub + n] = (bf16_t)v;
                else     ((float*)Cm)[(size_t)m * Nsub + n] = v;
            }
        }
    }
}

__global__ void k_gemm_naive(const float* __restrict__ A, const float* __restrict__ B,
                             const float* __restrict__ bias, float* __restrict__ out,
                             int M, int N, int K, int act) {
    int idx = blockIdx.x * 256 + threadIdx.x;
    if (idx >= M * N) return;
    int m = idx / N, n = idx % N;
    float s = bias[n];
    for (int k = 0; k < K; ++k)
        s += A[(size_t)m * K + k] * B[(size_t)k * N + n];
    if (act && s < 0.f) s *= 0.01f;
    out[idx] = s;
}

// ------- attention scores: one wave per (edge, local head), bf16x4 loads -------
__global__ void k_score(const bf16_t* __restrict__ xl, const bf16_t* __restrict__ xr,
                        const float* __restrict__ att, const int* __restrict__ srcA,
                        const int* __restrict__ dstA, float* __restrict__ sc,
                        int C, int HG, int h0) {
    int wid = (blockIdx.x * 256 + threadIdx.x) >> 6;
    int lane = threadIdx.x & 63;
    if (wid >= ETOT * HG) return;
    int e = wid / HG, hl = wid % HG;
    int s = srcA[e], d = dstA[e];
    const bf16x4* pl = (const bf16x4*)(xl + ((size_t)s * HG + hl) * C);
    const bf16x4* pr = (const bf16x4*)(xr + ((size_t)d * HG + hl) * C);
    const float4* pa = (const float4*)(att + (size_t)(h0 + hl) * C);
    float acc = 0.f;
    int C4 = C >> 2;
    for (int c = lane; c < C4; c += 64) {
        bf16x4 a = pl[c], b = pr[c];
        float4 w = pa[c];
        float v;
        v = (float)a[0] + (float)b[0]; v = v > 0.f ? v : 0.2f * v; acc += v * w.x;
        v = (float)a[1] + (float)b[1]; v = v > 0.f ? v : 0.2f * v; acc += v * w.y;
        v = (float)a[2] + (float)b[2]; v = v > 0.f ? v : 0.2f * v; acc += v * w.z;
        v = (float)a[3] + (float)b[3]; v = v > 0.f ? v : 0.2f * v; acc += v * w.w;
    }
#pragma unroll
    for (int off = 32; off; off >>= 1) acc += __shfl_down(acc, off, 64);
    if (lane == 0) sc[(size_t)e * HH + h0 + hl] = acc;
}

// ---------------- softmax per (dst, head) over incoming edges -----------------
__global__ void k_softmax(const int* __restrict__ off, const int* __restrict__ csre,
                          float* __restrict__ sc, int HG, int h0) {
    int idx = blockIdx.x * 256 + threadIdx.x;
    if (idx >= NN * HG) return;
    int d = idx / HG, h = h0 + idx % HG;
    int b = off[d], en = off[d + 1];
    float m = -1e30f;
    for (int i = b; i < en; ++i) m = fmaxf(m, sc[(size_t)csre[i] * HH + h]);
    float ssum = 0.f;
    for (int i = b; i < en; ++i) ssum += expf(sc[(size_t)csre[i] * HH + h] - m);
    float inv = 1.f / ssum;
    for (int i = b; i < en; ++i) {
        size_t p = (size_t)csre[i] * HH + h;
        sc[p] = expf(sc[p] - m) * inv;
    }
}

// ------- aggregate: block = (dst, c4-tile), thread = (hl, c4i) ---------------
__global__ __launch_bounds__(256) void k_aggregate(
        const bf16_t* __restrict__ xl, const float* __restrict__ sc,
        const int* __restrict__ off, const int* __restrict__ csre,
        const int* __restrict__ srcA, const float* __restrict__ bias,
        float* __restrict__ z, int C, int HG, int h0, int lgNC,
        int first, int last, int act) {
    __shared__ float4 sh[256];
    int d = blockIdx.x;
    int NC = 1 << lgNC;
    int c4i = threadIdx.x & (NC - 1);
    int hl = threadIdx.x >> lgNC;
    int c4 = blockIdx.y * NC + c4i;
    int C4 = C >> 2;
    bool active = (c4 < C4);
    float4 acc = {0.f, 0.f, 0.f, 0.f};
    int b = off[d], en = off[d + 1];
    for (int i = b; i < en; ++i) {
        int e = csre[i];
        int s = srcA[e];
        float w = sc[(size_t)e * HH + h0 + hl];
        if (active) {
            bf16x4 vx = *((const bf16x4*)(xl + ((size_t)s * HG + hl) * C) + c4);
            acc.x += w * (float)vx[0];
            acc.y += w * (float)vx[1];
            acc.z += w * (float)vx[2];
            acc.w += w * (float)vx[3];
        }
    }
    sh[threadIdx.x] = acc;
    __syncthreads();
    for (int s = HG >> 1; s >= 1; s >>= 1) {
        if (hl < s) {
            float4 o = sh[threadIdx.x + (s << lgNC)];
            float4 m = sh[threadIdx.x];
            m.x += o.x; m.y += o.y; m.z += o.z; m.w += o.w;
            sh[threadIdx.x] = m;
        }
        __syncthreads();
    }
    if (hl == 0 && active) {
        acc = sh[threadIdx.x];
        float4* zp = (float4*)(z + (size_t)d * C) + c4;
        if (!first) {
            float4 prev = *zp;
            acc.x += prev.x; acc.y += prev.y; acc.z += prev.z; acc.w += prev.w;
        }
        if (last) {
            const float4 bz = *((const float4*)bias + c4);
            acc.x = acc.x * (1.f / 32.f) + bz.x;
            acc.y = acc.y * (1.f / 32.f) + bz.y;
            acc.z = acc.z * (1.f / 32.f) + bz.z;
            acc.w = acc.w * (1.f / 32.f) + bz.w;
            if (act) {
                acc.x = acc.x < 0.f ? acc.x * 0.01f : acc.x;
                acc.y = acc.y < 0.f ? acc.y * 0.01f : acc.y;
                acc.z = acc.z < 0.f ? acc.z * 0.01f : acc.z;
                acc.w = acc.w < 0.f ? acc.w * 0.01f : acc.w;
            }
        }
        *zp = acc;
    }
}

// ---------------- host ----------------
extern "C" void kernel_launch(void* const* d_in, const int* in_sizes, int n_in,
                              void* d_out, int out_size, void* d_ws, size_t ws_size,
                              hipStream_t stream) {
    const float* x   = (const float*)d_in[0];
    const int* ei    = (const int*)d_in[1];
    const float* w1l = (const float*)d_in[2];  const float* b1l = (const float*)d_in[3];
    const float* w1r = (const float*)d_in[4];  const float* b1r = (const float*)d_in[5];
    const float* att1= (const float*)d_in[6];  const float* gb1 = (const float*)d_in[7];
    const float* w2l = (const float*)d_in[8];  const float* b2l = (const float*)d_in[9];
    const float* w2r = (const float*)d_in[10]; const float* b2r = (const float*)d_in[11];
    const float* att2= (const float*)d_in[12]; const float* gb2 = (const float*)d_in[13];
    const float* w3l = (const float*)d_in[14]; const float* b3l = (const float*)d_in[15];
    const float* w3r = (const float*)d_in[16]; const float* b3r = (const float*)d_in[17];
    const float* att3= (const float*)d_in[18]; const float* gb3 = (const float*)d_in[19];
    const float* dw1 = (const float*)d_in[20]; const float* db1 = (const float*)d_in[21];
    const float* dw2 = (const float*)d_in[22]; const float* db2 = (const float*)d_in[23];
    const float* dw3 = (const float*)d_in[24]; const float* db3 = (const float*)d_in[25];
    float* outp = (float*)d_out;

    char* p = (char*)d_ws;
    auto alloc = [&](size_t bytes) -> char* {
        char* r = p;
        p += (bytes + 255) & ~(size_t)255;
        return r;
    };
    float* sc   = (float*)alloc((size_t)ETOT * HH * 4);
    float* za   = (float*)alloc((size_t)NN * 1028 * 4);
    float* zb   = (float*)alloc((size_t)NN * 1028 * 4);
    bf16_t* Abf = (bf16_t*)alloc((size_t)NN * 1056 * 2);
    int*   ints = (int*)  alloc((size_t)(2 * NN + 16) * 4);
    int* cnt  = ints;
    int* cur  = ints + NN;
    int* flag = ints + 2 * NN;
    int* offp = (int*)alloc((size_t)(NN + 1) * 4);
    int* csre = (int*)alloc((size_t)ETOT * 4);
    int* srcA = (int*)alloc((size_t)ETOT * 4);
    int* dstA = (int*)alloc((size_t)ETOT * 4);
    size_t used = (size_t)(p - (char*)d_ws);
    size_t remain = (ws_size > used) ? (ws_size - used) : 0;
    char* chunk = p;

    k_zero_int<<<dim3((2 * NN + 16 + 255) / 256), dim3(256), 0, stream>>>(ints, 2 * NN + 16);
    k_detect<<<dim3((EE + 255) / 256), dim3(256), 0, stream>>>(ei, flag);
    k_edge_prep<<<dim3((ETOT + 255) / 256), dim3(256), 0, stream>>>(ei, flag, srcA, dstA, cnt);
    k_scan<<<dim3(1), dim3(NN), 0, stream>>>(cnt, offp);
    k_fill<<<dim3((ETOT + 255) / 256), dim3(256), 0, stream>>>(dstA, offp, cur, csre);

    struct Layer {
        const float* in; int cin; int C;
        const float *wl, *bl, *wr, *br, *att, *gb;
        float* zout; int act;
    };
    Layer L[3] = {
        { x,    4, 128,  w1l, b1l, w1r, b1r, att1, gb1, za, 1 },
        { za, 128, 512,  w2l, b2l, w2r, b2r, att2, gb2, zb, 1 },
        { zb, 512, 1028, w3l, b3l, w3r, b3r, att3, gb3, za, 0 },
    };
    auto al = [](size_t n) { return (n + 127) & ~(size_t)127; };

    for (int li = 0; li < 3; ++li) {
        int C = L[li].C, K = L[li].cin;
        bool mfma = (K >= 128);
        int Kp = (K + 31) & ~31;
        // per-head chunk bytes: xl + xr bf16 (+ Bt for mfma path)
        size_t perHG = 2ull * NN * C * 2 + (mfma ? (size_t)C * Kp * 2 : 0);
        int HG = 32;
        // 1MB slack: gload_lds staging may over-read up to one 128-row panel
        while (HG > 1 && (size_t)HG * perHG + (1u << 20) > remain) HG >>= 1;
        int nchunk = HH / HG;
        int lgNC = 0;
        while ((1 << lgNC) * HG < 256) ++lgNC;   // NC = 256/HG
        int NC = 1 << lgNC;
        bf16_t* xlc = (bf16_t*)chunk;
        bf16_t* xrc = xlc + al((size_t)NN * HG * C);
        bf16_t* Bt  = xrc + al((size_t)NN * HG * C);

        if (mfma)
            k_convA<<<dim3((NN * Kp + 255) / 256), dim3(256), 0, stream>>>(L[li].in, Abf, NN, K, Kp);

        for (int hg = 0; hg < nchunk; ++hg) {
            int h0 = hg * HG;
            int colOff = h0 * C;
            int Nsub = HG * C;
            if (mfma) {
                dim3 gc((Nsub + 31) / 32, Kp / 32);
                dim3 gg((Nsub + 127) / 128, NN / 128);
                k_convB<<<gc, dim3(256), 0, stream>>>(L[li].wl + colOff, Bt, K, Nsub, HH * C, Kp);
                k_gemm_bf16<<<gg, dim3(256), 0, stream>>>(Abf, Bt, L[li].bl + colOff, xlc, NN, Nsub, Kp, 0, 1);
                k_convB<<<gc, dim3(256), 0, stream>>>(L[li].wr + colOff, Bt, K, Nsub, HH * C, Kp);
                k_gemm_bf16<<<gg, dim3(256), 0, stream>>>(Abf, Bt, L[li].br + colOff, xrc, NN, Nsub, Kp, 0, 1);
            } else {
                dim3 gg((Nsub + TN - 1) / TN, (NN + TM - 1) / TM);
                k_gemm<<<gg, dim3(256), 0, stream>>>(L[li].in, L[li].wl + colOff, L[li].bl + colOff,
                                                     xlc, NN, Nsub, K, HH * C, 0, 1);
                k_gemm<<<gg, dim3(256), 0, stream>>>(L[li].in, L[li].wr + colOff, L[li].br + colOff,
                                                     xrc, NN, Nsub, K, HH * C, 0, 1);
            }
            int waves = ETOT * HG;
            k_score<<<dim3((waves * 64 + 255) / 256), dim3(256), 0, stream>>>(
                xlc, xrc, L[li].att, srcA, dstA, sc, C, HG, h0);
            k_softmax<<<dim3((NN * HG + 255) / 256), dim3(256), 0, stream>>>(offp, csre, sc, HG, h0);
            int C4 = C >> 2;
            dim3 ga(NN, (C4 + NC - 1) / NC);
            k_aggregate<<<ga, dim3(256), 0, stream>>>(xlc, sc, offp, csre, srcA, L[li].gb,
                                                      L[li].zout, C, HG, h0, lgNC,
                                                      hg == 0, hg == nchunk - 1, L[li].act);
        }
    }

    // ---- decoder ----
    {
        int K = 1028, Kp = 1056, Nsub = 512;
        bf16_t* Bt = (bf16_t*)chunk;
        k_convA<<<dim3((NN * Kp + 255) / 256), dim3(256), 0, stream>>>(za, Abf, NN, K, Kp);
        k_convB<<<dim3(Nsub / 32, Kp / 32), dim3(256), 0, stream>>>(dw1, Bt, K, Nsub, Nsub, Kp);
        k_gemm_bf16<<<dim3(Nsub / 128, NN / 128), dim3(256), 0, stream>>>(Abf, Bt, db1, zb, NN, Nsub, Kp, 1, 0);
    }
    k_gemm<<<dim3(128 / TN, NN / TM), dim3(256), 0, stream>>>(zb, dw2, db2, za, NN, 128, 512, 128, 1, 0);
    k_gemm_naive<<<dim3((NN * 2 + 255) / 256), dim3(256), 0, stream>>>(za, dw3, db3, outp, NN, 2, 128, 0);
}

// Round 5
// 679.926 us; speedup vs baseline: 1.5252x; 1.0733x over previous
//
#include <hip/hip_runtime.h>
#include <cstdint>
#include <cstddef>

#define NN 1024
#define EE 2048
#define ETOT 3072
#define HH 32

typedef __bf16 bf16_t;
typedef __attribute__((ext_vector_type(8))) __bf16 bf16x8;
typedef __attribute__((ext_vector_type(4))) __bf16 bf16x4;
typedef __attribute__((ext_vector_type(2))) __bf16 bf16x2;
typedef __attribute__((ext_vector_type(4))) float f32x4;

typedef const __attribute__((address_space(1))) void gvoid_t;
typedef __attribute__((address_space(3))) void lvoid_t;

// async global->LDS, 16B per lane. LDS dest = wave-uniform base + lane*16.
__device__ __forceinline__ void gll16(const void* g, void* l) {
    __builtin_amdgcn_global_load_lds((gvoid_t*)g, (lvoid_t*)l, 16, 0, 0);
}

// ---------------- utility ----------------
__global__ void k_zero_int(int* p, int n) {
    int i = blockIdx.x * 256 + threadIdx.x;
    if (i < n) p[i] = 0;
}

__global__ void k_detect(const int* ei, int* flag) {
    int i = blockIdx.x * 256 + threadIdx.x;
    int idx = 2 * i + 1;
    if (idx < 2 * EE && ei[idx] != 0) atomicOr(flag, 1);
}

__global__ void k_edge_prep(const int* ei, const int* flag, int* srcA, int* dstA, int* cnt) {
    int e = blockIdx.x * 256 + threadIdx.x;
    if (e >= ETOT) return;
    int s, d;
    if (e < EE) {
        if (*flag) { s = ei[e]; d = ei[EE + e]; }
        else       { s = ei[2 * e]; d = ei[2 * (EE + e)]; }
        s &= (NN - 1); d &= (NN - 1);
    } else {
        s = d = e - EE;
    }
    srcA[e] = s; dstA[e] = d;
    atomicAdd(&cnt[d], 1);
}

__global__ void k_scan(const int* cnt, int* off) {
    __shared__ int sh[NN];
    int t = threadIdx.x;
    sh[t] = cnt[t];
    __syncthreads();
    for (int o = 1; o < NN; o <<= 1) {
        int v = (t >= o) ? sh[t - o] : 0;
        __syncthreads();
        sh[t] += v;
        __syncthreads();
    }
    off[t + 1] = sh[t];
    if (t == 0) off[0] = 0;
}

__global__ void k_fill(const int* dstA, const int* off, int* cur, int* csre) {
    int e = blockIdx.x * 256 + threadIdx.x;
    if (e >= ETOT) return;
    int d = dstA[e];
    int p = atomicAdd(&cur[d], 1);
    csre[off[d] + p] = e;
}

// ---------------- fp32 -> bf16 converts ----------------
__global__ void k_convA(const float* __restrict__ A, bf16_t* __restrict__ Ab,
                        int M, int K, int Kp) {
    int idx = blockIdx.x * 256 + threadIdx.x;
    if (idx >= M * Kp) return;
    int m = idx / Kp, k = idx % Kp;
    Ab[idx] = (k < K) ? (bf16_t)A[(size_t)m * K + k] : (bf16_t)0.f;
}

// transpose-convert: B[K][ldb] fp32 -> Bt[Nsub][Kp] bf16. bf16x4 writes (8B/lane),
// lanes 0-7 cover one contiguous 64B row segment -> coalesced.
__global__ void k_convB(const float* __restrict__ B, bf16_t* __restrict__ Bt,
                        int K, int Nsub, int ldb, int Kp) {
    __shared__ float sh[32][33];
    int kt = blockIdx.y * 32, nt = blockIdx.x * 32;
    int tx = threadIdx.x & 31, ty = threadIdx.x >> 5;
#pragma unroll
    for (int i = 0; i < 4; ++i) {
        int k = kt + ty + i * 8, n = nt + tx;
        sh[ty + i * 8][tx] = (k < K && n < Nsub) ? B[(size_t)k * ldb + n] : 0.f;
    }
    __syncthreads();
    int kq = (threadIdx.x & 7) * 4;    // k group of 4
    int nl = threadIdx.x >> 3;         // 0..31
    int n = nt + nl;
    if (n < Nsub) {
        bf16x4 v;
        v[0] = (bf16_t)sh[kq][nl];
        v[1] = (bf16_t)sh[kq + 1][nl];
        v[2] = (bf16_t)sh[kq + 2][nl];
        v[3] = (bf16_t)sh[kq + 3][nl];
        *(bf16x4*)(&Bt[(size_t)n * Kp + kt + kq]) = v;
    }
}

// ------- bf16 MFMA GEMM: 3-buffer depth-2 pipeline, counted vmcnt (T4) -------
// C[M x Nsub] = Ab[M x Kp] @ Bt[Nsub x Kp]^T + bias; output fp32 or bf16 (obf).
// Per iter: waitcnt(vmcnt(4)) -> s_barrier -> stage(t+2) -> ds_read(t) -> MFMA.
// vmcnt never drains to 0 mid-loop; tile t's loads have ~2 iterations to land.
__global__ __launch_bounds__(256) void k_gemm_bf16(
        const bf16_t* __restrict__ Ab, const bf16_t* __restrict__ Bt,
        const float* __restrict__ bias, void* __restrict__ Cm,
        int M, int Nsub, int Kp, int act, int obf) {
    __shared__ __align__(16) bf16_t SH[24576];   // 48KB: 3 bufs x (A 8KB + B 8KB)
    int tid = threadIdx.x;
    int wave = tid >> 6, lane = tid & 63;
    int wm = (wave & 1) * 64, wn = (wave >> 1) * 64;
    int l16 = lane & 15, lq = lane >> 4;

    // XCD-aware remap (y fastest within each chunk)
    int nx = gridDim.x, ny = gridDim.y;
    int bx = blockIdx.x, by = blockIdx.y;
    int total = nx * ny;
    if ((total & 7) == 0) {
        int j = bx + nx * by;
        int w = (j & 7) * (total >> 3) + (j >> 3);
        bx = w / ny;
        by = w % ny;
    }
    int m0 = by * 128, n0 = bx * 128;

    // staging: 8KB per tile = 512 x 16B units; unit u -> row r = u>>2, slot u&3.
    // global source slot = lds slot ^ ((r>>1)&3)  (involution; undone on read)
    int u0 = wave * 128 + lane;
    int u1 = u0 + 64;
    int r0 = u0 >> 2, s0 = u0 & 3;
    int r1 = u1 >> 2, s1 = u1 & 3;
    int c0 = ((s0 ^ ((r0 >> 1) & 3)) << 3);   // bf16 elements within row
    int c1 = ((s1 ^ ((r1 >> 1) & 3)) << 3);
    const bf16_t* gA0 = Ab + (size_t)(m0 + r0) * Kp + c0;
    const bf16_t* gA1 = Ab + (size_t)(m0 + r1) * Kp + c1;
    const bf16_t* gB0 = Bt + (size_t)(n0 + r0) * Kp + c0;
    const bf16_t* gB1 = Bt + (size_t)(n0 + r1) * Kp + c1;

    // fragment-read swizzle (same involution)
    int cR = ((lq ^ ((l16 >> 1) & 3)) << 3);

    f32x4 acc[4][4] = {};
    int nt = Kp >> 5;

    // prologue: stage tiles 0,1 into bufs 0,1
#pragma unroll
    for (int pt = 0; pt < 2; ++pt) {
        bf16_t* d = SH + pt * 8192 + wave * 1024;
        gll16(gA0, d); gll16(gA1, d + 512);
        gll16(gB0, d + 4096); gll16(gB1, d + 4096 + 512);
        gA0 += 32; gA1 += 32; gB0 += 32; gB1 += 32;
    }

    int bc = 0, bn = 2;   // current read buf, next stage buf
    for (int t = 0; t < nt; ++t) {
        if (t + 1 < nt)
            asm volatile("s_waitcnt vmcnt(4) lgkmcnt(0)" ::: "memory");
        else
            asm volatile("s_waitcnt vmcnt(0) lgkmcnt(0)" ::: "memory");
        asm volatile("s_barrier" ::: "memory");
        __builtin_amdgcn_sched_barrier(0);
        if (t + 2 < nt) {
            bf16_t* d = SH + bn * 8192 + wave * 1024;
            gll16(gA0, d); gll16(gA1, d + 512);
            gll16(gB0, d + 4096); gll16(gB1, d + 4096 + 512);
            gA0 += 32; gA1 += 32; gB0 += 32; gB1 += 32;
        }
        const bf16_t* rb = SH + bc * 8192;
        bf16x8 af[4], bfr[4];
#pragma unroll
        for (int mi = 0; mi < 4; ++mi)
            af[mi] = *(const bf16x8*)(rb + (wm + mi * 16 + l16) * 32 + cR);
#pragma unroll
        for (int ni = 0; ni < 4; ++ni)
            bfr[ni] = *(const bf16x8*)(rb + 4096 + (wn + ni * 16 + l16) * 32 + cR);
#pragma unroll
        for (int mi = 0; mi < 4; ++mi)
#pragma unroll
            for (int ni = 0; ni < 4; ++ni)
                acc[mi][ni] = __builtin_amdgcn_mfma_f32_16x16x32_bf16(
                    af[mi], bfr[ni], acc[mi][ni], 0, 0, 0);
        bc = (bc == 2) ? 0 : bc + 1;
        bn = (bn == 2) ? 0 : bn + 1;
    }
    // all waves done with LDS before epilogue reuses it
    asm volatile("s_waitcnt lgkmcnt(0)" ::: "memory");
    asm volatile("s_barrier" ::: "memory");
    __builtin_amdgcn_sched_barrier(0);

    if (obf) {
        // ---- LDS re-layout epilogue: coalesced bf16x8 C stores ----
#pragma unroll
        for (int ni = 0; ni < 4; ++ni) {
            int cl = wn + ni * 16 + l16;
            float bv = bias[n0 + cl];
#pragma unroll
            for (int mi = 0; mi < 4; ++mi)
#pragma unroll
                for (int r = 0; r < 4; ++r) {
                    int rl = wm + mi * 16 + lq * 4 + r;
                    float v = acc[mi][ni][r] + bv;
                    if (act && v < 0.f) v *= 0.01f;
                    int slot = ((cl >> 3) ^ (rl & 7)) & 15;
                    SH[rl * 128 + slot * 8 + (cl & 7)] = (bf16_t)v;
                }
        }
        __syncthreads();
        bf16_t* Cb = (bf16_t*)Cm;
#pragma unroll
        for (int i = 0; i < 8; ++i) {
            int j = i * 2048 + tid * 8;       // bf16 index into SH
            int rl = j >> 7;
            int p = (j >> 3) & 15;
            int cl = ((p ^ (rl & 7)) & 15) * 8;
            bf16x8 v = *(const bf16x8*)(SH + rl * 128 + p * 8);
            int row = m0 + rl, col = n0 + cl;
            if (row < M) {
                if (col + 7 < Nsub) {
                    *(bf16x8*)(Cb + (size_t)row * Nsub + col) = v;
                } else {
#pragma unroll
                    for (int e = 0; e < 8; ++e)
                        if (col + e < Nsub) Cb[(size_t)row * Nsub + col + e] = v[e];
                }
            }
        }
    } else {
        // fp32 output path (decoder): direct stores
#pragma unroll
        for (int ni = 0; ni < 4; ++ni) {
            int col = n0 + wn + ni * 16 + l16;
            if (col >= Nsub) continue;
            float bv = bias[col];
#pragma unroll
            for (int mi = 0; mi < 4; ++mi)
#pragma unroll
                for (int r = 0; r < 4; ++r) {
                    int row = m0 + wm + mi * 16 + lq * 4 + r;
                    if (row < M) {
                        float v = acc[mi][ni][r] + bv;
                        if (act && v < 0.f) v *= 0.01f;
                        ((float*)Cm)[(size_t)row * Nsub + col] = v;
                    }
                }
        }
    }
}

// ------- fp32 GEMM (layer-1): 64x64 tile, 4x4/thread, BK=16 -------
#define TM 64
#define TN 64
#define TK 16
__global__ __launch_bounds__(256) void k_gemm(
        const float* __restrict__ A, const float* __restrict__ B,
        const float* __restrict__ bias, void* __restrict__ Cm,
        int M, int Nsub, int K, int ldb, int act, int obf) {
    __shared__ float As[TK][TM];
    __shared__ float Bs[TK][TN];
    int tid = threadIdx.x;
    int tx = tid % 16, ty = tid / 16;
    int m0 = blockIdx.y * TM, n0 = blockIdx.x * TN;
    float acc[4][4] = {};
    for (int k0 = 0; k0 < K; k0 += TK) {
#pragma unroll
        for (int i = 0; i < 4; ++i) {
            int idx = tid * 4 + i;
            int m = idx >> 4, k = idx & 15;
            float v = 0.f;
            if (k0 + k < K && m0 + m < M) v = A[(size_t)(m0 + m) * K + k0 + k];
            As[k][m] = v;
        }
#pragma unroll
        for (int i = 0; i < 4; ++i) {
            int idx = tid * 4 + i;
            int k = idx >> 6, n = idx & 63;
            float v = 0.f;
            if (k0 + k < K && n0 + n < Nsub) v = B[(size_t)(k0 + k) * ldb + n0 + n];
            Bs[k][n] = v;
        }
        __syncthreads();
#pragma unroll
        for (int kk = 0; kk < TK; ++kk) {
            float4 a4 = *(const float4*)&As[kk][ty * 4];
            float4 b4 = *(const float4*)&Bs[kk][tx * 4];
            float af[4] = {a4.x, a4.y, a4.z, a4.w};
            float bf[4] = {b4.x, b4.y, b4.z, b4.w};
#pragma unroll
            for (int i = 0; i < 4; ++i)
#pragma unroll
                for (int j = 0; j < 4; ++j)
                    acc[i][j] += af[i] * bf[j];
        }
        __syncthreads();
    }
#pragma unroll
    for (int i = 0; i < 4; ++i) {
        int m = m0 + ty * 4 + i;
        if (m >= M) continue;
#pragma unroll
        for (int j = 0; j < 4; ++j) {
            int n = n0 + tx * 4 + j;
            if (n < Nsub) {
                float v = acc[i][j] + bias[n];
                if (act && v < 0.f) v *= 0.01f;
                if (obf) ((bf16_t*)Cm)[(size_t)m * Nsub + n] = (bf16_t)v;
                else     ((float*)Cm)[(size_t)m * Nsub + n] = v;
            }
        }
    }
}

__global__ void k_gemm_naive(const float* __restrict__ A, const float* __restrict__ B,
                             const float* __restrict__ bias, float* __restrict__ out,
                             int M, int N, int K, int act) {
    int idx = blockIdx.x * 256 + threadIdx.x;
    if (idx >= M * N) return;
    int m = idx / N, n = idx % N;
    float s = bias[n];
    for (int k = 0; k < K; ++k)
        s += A[(size_t)m * K + k] * B[(size_t)k * N + n];
    if (act && s < 0.f) s *= 0.01f;
    out[idx] = s;
}

// ------- attention scores: one wave per (edge, local head), bf16x4 loads -------
__global__ void k_score(const bf16_t* __restrict__ xl, const bf16_t* __restrict__ xr,
                        const float* __restrict__ att, const int* __restrict__ srcA,
                        const int* __restrict__ dstA, float* __restrict__ sc,
                        int C, int HG, int h0) {
    int wid = (blockIdx.x * 256 + threadIdx.x) >> 6;
    int lane = threadIdx.x & 63;
    if (wid >= ETOT * HG) return;
    int e = wid / HG, hl = wid % HG;
    int s = srcA[e], d = dstA[e];
    const bf16x4* pl = (const bf16x4*)(xl + ((size_t)s * HG + hl) * C);
    const bf16x4* pr = (const bf16x4*)(xr + ((size_t)d * HG + hl) * C);
    const float4* pa = (const float4*)(att + (size_t)(h0 + hl) * C);
    float acc = 0.f;
    int C4 = C >> 2;
    for (int c = lane; c < C4; c += 64) {
        bf16x4 a = pl[c], b = pr[c];
        float4 w = pa[c];
        float v;
        v = (float)a[0] + (float)b[0]; v = v > 0.f ? v : 0.2f * v; acc += v * w.x;
        v = (float)a[1] + (float)b[1]; v = v > 0.f ? v : 0.2f * v; acc += v * w.y;
        v = (float)a[2] + (float)b[2]; v = v > 0.f ? v : 0.2f * v; acc += v * w.z;
        v = (float)a[3] + (float)b[3]; v = v > 0.f ? v : 0.2f * v; acc += v * w.w;
    }
#pragma unroll
    for (int off = 32; off; off >>= 1) acc += __shfl_down(acc, off, 64);
    if (lane == 0) sc[(size_t)e * HH + h0 + hl] = acc;
}

// ---------------- softmax per (dst, head) over incoming edges -----------------
__global__ void k_softmax(const int* __restrict__ off, const int* __restrict__ csre,
                          float* __restrict__ sc, int HG, int h0) {
    int idx = blockIdx.x * 256 + threadIdx.x;
    if (idx >= NN * HG) return;
    int d = idx / HG, h = h0 + idx % HG;
    int b = off[d], en = off[d + 1];
    float m = -1e30f;
    for (int i = b; i < en; ++i) m = fmaxf(m, sc[(size_t)csre[i] * HH + h]);
    float ssum = 0.f;
    for (int i = b; i < en; ++i) ssum += expf(sc[(size_t)csre[i] * HH + h] - m);
    float inv = 1.f / ssum;
    for (int i = b; i < en; ++i) {
        size_t p = (size_t)csre[i] * HH + h;
        sc[p] = expf(sc[p] - m) * inv;
    }
}

// ------- aggregate: block = (dst, c4-tile), thread = (hl, c4i) ---------------
__global__ __launch_bounds__(256) void k_aggregate(
        const bf16_t* __restrict__ xl, const float* __restrict__ sc,
        const int* __restrict__ off, const int* __restrict__ csre,
        const int* __restrict__ srcA, const float* __restrict__ bias,
        float* __restrict__ z, int C, int HG, int h0, int lgNC,
        int first, int last, int act) {
    __shared__ float4 sh[256];
    int d = blockIdx.x;
    int NC = 1 << lgNC;
    int c4i = threadIdx.x & (NC - 1);
    int hl = threadIdx.x >> lgNC;
    int c4 = blockIdx.y * NC + c4i;
    int C4 = C >> 2;
    bool active = (c4 < C4);
    float4 acc = {0.f, 0.f, 0.f, 0.f};
    int b = off[d], en = off[d + 1];
    for (int i = b; i < en; ++i) {
        int e = csre[i];
        int s = srcA[e];
        float w = sc[(size_t)e * HH + h0 + hl];
        if (active) {
            bf16x4 vx = *((const bf16x4*)(xl + ((size_t)s * HG + hl) * C) + c4);
            acc.x += w * (float)vx[0];
            acc.y += w * (float)vx[1];
            acc.z += w * (float)vx[2];
            acc.w += w * (float)vx[3];
        }
    }
    sh[threadIdx.x] = acc;
    __syncthreads();
    for (int s = HG >> 1; s >= 1; s >>= 1) {
        if (hl < s) {
            float4 o = sh[threadIdx.x + (s << lgNC)];
            float4 m = sh[threadIdx.x];
            m.x += o.x; m.y += o.y; m.z += o.z; m.w += o.w;
            sh[threadIdx.x] = m;
        }
        __syncthreads();
    }
    if (hl == 0 && active) {
        acc = sh[threadIdx.x];
        float4* zp = (float4*)(z + (size_t)d * C) + c4;
        if (!first) {
            float4 prev = *zp;
            acc.x += prev.x; acc.y += prev.y; acc.z += prev.z; acc.w += prev.w;
        }
        if (last) {
            const float4 bz = *((const float4*)bias + c4);
            acc.x = acc.x * (1.f / 32.f) + bz.x;
            acc.y = acc.y * (1.f / 32.f) + bz.y;
            acc.z = acc.z * (1.f / 32.f) + bz.z;
            acc.w = acc.w * (1.f / 32.f) + bz.w;
            if (act) {
                acc.x = acc.x < 0.f ? acc.x * 0.01f : acc.x;
                acc.y = acc.y < 0.f ? acc.y * 0.01f : acc.y;
                acc.z = acc.z < 0.f ? acc.z * 0.01f : acc.z;
                acc.w = acc.w < 0.f ? acc.w * 0.01f : acc.w;
            }
        }
        *zp = acc;
    }
}

// ---------------- host ----------------
extern "C" void kernel_launch(void* const* d_in, const int* in_sizes, int n_in,
                              void* d_out, int out_size, void* d_ws, size_t ws_size,
                              hipStream_t stream) {
    const float* x   = (const float*)d_in[0];
    const int* ei    = (const int*)d_in[1];
    const float* w1l = (const float*)d_in[2];  const float* b1l = (const float*)d_in[3];
    const float* w1r = (const float*)d_in[4];  const float* b1r = (const float*)d_in[5];
    const float* att1= (const float*)d_in[6];  const float* gb1 = (const float*)d_in[7];
    const float* w2l = (const float*)d_in[8];  const float* b2l = (const float*)d_in[9];
    const float* w2r = (const float*)d_in[10]; const float* b2r = (const float*)d_in[11];
    const float* att2= (const float*)d_in[12]; const float* gb2 = (const float*)d_in[13];
    const float* w3l = (const float*)d_in[14]; const float* b3l = (const float*)d_in[15];
    const float* w3r = (const float*)d_in[16]; const float* b3r = (const float*)d_in[17];
    const float* att3= (const float*)d_in[18]; const float* gb3 = (const float*)d_in[19];
    const float* dw1 = (const float*)d_in[20]; const float* db1 = (const float*)d_in[21];
    const float* dw2 = (const float*)d_in[22]; const float* db2 = (const float*)d_in[23];
    const float* dw3 = (const float*)d_in[24]; const float* db3 = (const float*)d_in[25];
    float* outp = (float*)d_out;

    char* p = (char*)d_ws;
    auto alloc = [&](size_t bytes) -> char* {
        char* r = p;
        p += (bytes + 255) & ~(size_t)255;
        return r;
    };
    float* sc   = (float*)alloc((size_t)ETOT * HH * 4);
    float* za   = (float*)alloc((size_t)NN * 1028 * 4);
    float* zb   = (float*)alloc((size_t)NN * 1028 * 4);
    bf16_t* Abf = (bf16_t*)alloc((size_t)NN * 1056 * 2);
    int*   ints = (int*)  alloc((size_t)(2 * NN + 16) * 4);
    int* cnt  = ints;
    int* cur  = ints + NN;
    int* flag = ints + 2 * NN;
    int* offp = (int*)alloc((size_t)(NN + 1) * 4);
    int* csre = (int*)alloc((size_t)ETOT * 4);
    int* srcA = (int*)alloc((size_t)ETOT * 4);
    int* dstA = (int*)alloc((size_t)ETOT * 4);
    size_t used = (size_t)(p - (char*)d_ws);
    size_t remain = (ws_size > used) ? (ws_size - used) : 0;
    char* chunk = p;

    k_zero_int<<<dim3((2 * NN + 16 + 255) / 256), dim3(256), 0, stream>>>(ints, 2 * NN + 16);
    k_detect<<<dim3((EE + 255) / 256), dim3(256), 0, stream>>>(ei, flag);
    k_edge_prep<<<dim3((ETOT + 255) / 256), dim3(256), 0, stream>>>(ei, flag, srcA, dstA, cnt);
    k_scan<<<dim3(1), dim3(NN), 0, stream>>>(cnt, offp);
    k_fill<<<dim3((ETOT + 255) / 256), dim3(256), 0, stream>>>(dstA, offp, cur, csre);

    struct Layer {
        const float* in; int cin; int C;
        const float *wl, *bl, *wr, *br, *att, *gb;
        float* zout; int act;
    };
    Layer L[3] = {
        { x,    4, 128,  w1l, b1l, w1r, b1r, att1, gb1, za, 1 },
        { za, 128, 512,  w2l, b2l, w2r, b2r, att2, gb2, zb, 1 },
        { zb, 512, 1028, w3l, b3l, w3r, b3r, att3, gb3, za, 0 },
    };
    auto al = [](size_t n) { return (n + 127) & ~(size_t)127; };

    for (int li = 0; li < 3; ++li) {
        int C = L[li].C, K = L[li].cin;
        bool mfma = (K >= 128);
        int Kp = (K + 31) & ~31;
        // per-head chunk bytes: xl + xr bf16 (+ Bt for mfma path)
        size_t perHG = 2ull * NN * C * 2 + (mfma ? (size_t)C * Kp * 2 : 0);
        int HG = 32;
        // 1MB slack: gload_lds staging may over-read up to one 128-row panel
        while (HG > 1 && (size_t)HG * perHG + (1u << 20) > remain) HG >>= 1;
        int nchunk = HH / HG;
        int lgNC = 0;
        while ((1 << lgNC) * HG < 256) ++lgNC;   // NC = 256/HG
        int NC = 1 << lgNC;
        bf16_t* xlc = (bf16_t*)chunk;
        bf16_t* xrc = xlc + al((size_t)NN * HG * C);
        bf16_t* Bt  = xrc + al((size_t)NN * HG * C);

        if (mfma)
            k_convA<<<dim3((NN * Kp + 255) / 256), dim3(256), 0, stream>>>(L[li].in, Abf, NN, K, Kp);

        for (int hg = 0; hg < nchunk; ++hg) {
            int h0 = hg * HG;
            int colOff = h0 * C;
            int Nsub = HG * C;
            if (mfma) {
                dim3 gc((Nsub + 31) / 32, Kp / 32);
                dim3 gg((Nsub + 127) / 128, NN / 128);
                k_convB<<<gc, dim3(256), 0, stream>>>(L[li].wl + colOff, Bt, K, Nsub, HH * C, Kp);
                k_gemm_bf16<<<gg, dim3(256), 0, stream>>>(Abf, Bt, L[li].bl + colOff, xlc, NN, Nsub, Kp, 0, 1);
                k_convB<<<gc, dim3(256), 0, stream>>>(L[li].wr + colOff, Bt, K, Nsub, HH * C, Kp);
                k_gemm_bf16<<<gg, dim3(256), 0, stream>>>(Abf, Bt, L[li].br + colOff, xrc, NN, Nsub, Kp, 0, 1);
            } else {
                dim3 gg((Nsub + TN - 1) / TN, (NN + TM - 1) / TM);
                k_gemm<<<gg, dim3(256), 0, stream>>>(L[li].in, L[li].wl + colOff, L[li].bl + colOff,
                                                     xlc, NN, Nsub, K, HH * C, 0, 1);
                k_gemm<<<gg, dim3(256), 0, stream>>>(L[li].in, L[li].wr + colOff, L[li].br + colOff,
                                                     xrc, NN, Nsub, K, HH * C, 0, 1);
            }
            int waves = ETOT * HG;
            k_score<<<dim3((waves * 64 + 255) / 256), dim3(256), 0, stream>>>(
                xlc, xrc, L[li].att, srcA, dstA, sc, C, HG, h0);
            k_softmax<<<dim3((NN * HG + 255) / 256), dim3(256), 0, stream>>>(offp, csre, sc, HG, h0);
            int C4 = C >> 2;
            dim3 ga(NN, (C4 + NC - 1) / NC);
            k_aggregate<<<ga, dim3(256), 0, stream>>>(xlc, sc, offp, csre, srcA, L[li].gb,
                                                      L[li].zout, C, HG, h0, lgNC,
                                                      hg == 0, hg == nchunk - 1, L[li].act);
        }
    }

    // ---- decoder: all three layers on the MFMA path ----
    {
        // chunk layout: Bt1 (512x1056 bf16) | AbD2 (1024x512 bf16) | Bt2 (128x512 bf16)
        bf16_t* Bt1  = (bf16_t*)chunk;
        bf16_t* AbD2 = Bt1 + al((size_t)512 * 1056);
        bf16_t* Bt2  = AbD2 + al((size_t)NN * 512);

        // decoder-1: 1028 -> 512, LeakyReLU, bf16 output straight into AbD2
        k_convA<<<dim3((NN * 1056 + 255) / 256), dim3(256), 0, stream>>>(za, Abf, NN, 1028, 1056);
        k_convB<<<dim3(512 / 32, 1056 / 32), dim3(256), 0, stream>>>(dw1, Bt1, 1028, 512, 512, 1056);
        k_gemm_bf16<<<dim3(512 / 128, NN / 128), dim3(256), 0, stream>>>(Abf, Bt1, db1, AbD2, NN, 512, 1056, 1, 1);

        // decoder-2: 512 -> 128, LeakyReLU, fp32 output into za (was the 63us k_gemm)
        k_convB<<<dim3(128 / 32, 512 / 32), dim3(256), 0, stream>>>(dw2, Bt2, 512, 128, 128, 512);
        k_gemm_bf16<<<dim3(128 / 128, NN / 128), dim3(256), 0, stream>>>(AbD2, Bt2, db2, za, NN, 128, 512, 1, 0);
    }
    k_gemm_naive<<<dim3((NN * 2 + 255) / 256), dim3(256), 0, stream>>>(za, dw3, db3, outp, NN, 2, 128, 0);
}

// Round 6
// 678.210 us; speedup vs baseline: 1.5291x; 1.0025x over previous
//
#include <hip/hip_runtime.h>
#include <cstdint>
#include <cstddef>

#define NN 1024
#define EE 2048
#define ETOT 3072
#define HH 32

typedef __bf16 bf16_t;
typedef __attribute__((ext_vector_type(8))) __bf16 bf16x8;
typedef __attribute__((ext_vector_type(4))) __bf16 bf16x4;
typedef __attribute__((ext_vector_type(2))) __bf16 bf16x2;
typedef __attribute__((ext_vector_type(4))) float f32x4;

typedef const __attribute__((address_space(1))) void gvoid_t;
typedef __attribute__((address_space(3))) void lvoid_t;

// async global->LDS, 16B per lane. LDS dest = wave-uniform base + lane*16.
__device__ __forceinline__ void gll16(const void* g, void* l) {
    __builtin_amdgcn_global_load_lds((gvoid_t*)g, (lvoid_t*)l, 16, 0, 0);
}

// ---------------- utility ----------------
__global__ void k_zero_int(int* p, int n) {
    int i = blockIdx.x * 256 + threadIdx.x;
    if (i < n) p[i] = 0;
}

__global__ void k_detect(const int* ei, int* flag) {
    int i = blockIdx.x * 256 + threadIdx.x;
    int idx = 2 * i + 1;
    if (idx < 2 * EE && ei[idx] != 0) atomicOr(flag, 1);
}

__global__ void k_edge_prep(const int* ei, const int* flag, int* srcA, int* dstA, int* cnt) {
    int e = blockIdx.x * 256 + threadIdx.x;
    if (e >= ETOT) return;
    int s, d;
    if (e < EE) {
        if (*flag) { s = ei[e]; d = ei[EE + e]; }
        else       { s = ei[2 * e]; d = ei[2 * (EE + e)]; }
        s &= (NN - 1); d &= (NN - 1);
    } else {
        s = d = e - EE;
    }
    srcA[e] = s; dstA[e] = d;
    atomicAdd(&cnt[d], 1);
}

__global__ void k_scan(const int* cnt, int* off) {
    __shared__ int sh[NN];
    int t = threadIdx.x;
    sh[t] = cnt[t];
    __syncthreads();
    for (int o = 1; o < NN; o <<= 1) {
        int v = (t >= o) ? sh[t - o] : 0;
        __syncthreads();
        sh[t] += v;
        __syncthreads();
    }
    off[t + 1] = sh[t];
    if (t == 0) off[0] = 0;
}

__global__ void k_fill(const int* dstA, const int* off, int* cur, int* csre) {
    int e = blockIdx.x * 256 + threadIdx.x;
    if (e >= ETOT) return;
    int d = dstA[e];
    int p = atomicAdd(&cur[d], 1);
    csre[off[d] + p] = e;
}

// ---------------- fp32 -> bf16 converts ----------------
__global__ void k_convA(const float* __restrict__ A, bf16_t* __restrict__ Ab,
                        int M, int K, int Kp) {
    int idx = blockIdx.x * 256 + threadIdx.x;
    if (idx >= M * Kp) return;
    int m = idx / Kp, k = idx % Kp;
    Ab[idx] = (k < K) ? (bf16_t)A[(size_t)m * K + k] : (bf16_t)0.f;
}

// transpose-convert: B[K][ldb] fp32 -> Bt[Nsub][Kp] bf16. bf16x4 writes (8B/lane),
// lanes 0-7 cover one contiguous 64B row segment -> coalesced.
__global__ void k_convB(const float* __restrict__ B, bf16_t* __restrict__ Bt,
                        int K, int Nsub, int ldb, int Kp) {
    __shared__ float sh[32][33];
    int kt = blockIdx.y * 32, nt = blockIdx.x * 32;
    int tx = threadIdx.x & 31, ty = threadIdx.x >> 5;
#pragma unroll
    for (int i = 0; i < 4; ++i) {
        int k = kt + ty + i * 8, n = nt + tx;
        sh[ty + i * 8][tx] = (k < K && n < Nsub) ? B[(size_t)k * ldb + n] : 0.f;
    }
    __syncthreads();
    int kq = (threadIdx.x & 7) * 4;    // k group of 4
    int nl = threadIdx.x >> 3;         // 0..31
    int n = nt + nl;
    if (n < Nsub) {
        bf16x4 v;
        v[0] = (bf16_t)sh[kq][nl];
        v[1] = (bf16_t)sh[kq + 1][nl];
        v[2] = (bf16_t)sh[kq + 2][nl];
        v[3] = (bf16_t)sh[kq + 3][nl];
        *(bf16x4*)(&Bt[(size_t)n * Kp + kt + kq]) = v;
    }
}

// ------- bf16 MFMA GEMM: 128x128 tile, BK=64, 2-buffer T3-minimum pipeline ----
// C[M x Nsub] = Ab[M x Kp] @ Bt[Nsub x Kp]^T + bias; output fp32 or bf16 (obf).
// Per K-tile (64): STAGE(t+1 -> buf^1) ; ds_read(t) ; 32 MFMA ; vmcnt(0)+barrier.
// Load latency hides under the current tile's ds_read+MFMA; barriers/waits halve
// vs BK=32. LDS 64KB -> 2 blocks/CU.
// Swizzle (rule #21, rows = 64 bf16 = 128B = exact 32-bank alias): 8 slots of
// 16B per row; involution slot ^= (row&7) applied on the GLOBAL source and on
// the fragment read; LDS stays linear for global_load_lds.
__global__ __launch_bounds__(256) void k_gemm_bf16(
        const bf16_t* __restrict__ Ab, const bf16_t* __restrict__ Bt,
        const float* __restrict__ bias, void* __restrict__ Cm,
        int M, int Nsub, int Kp, int act, int obf) {
    __shared__ __align__(16) bf16_t SH[32768];   // 64KB: 2 bufs x (A 16KB + B 16KB)
    int tid = threadIdx.x;
    int wave = tid >> 6, lane = tid & 63;
    int wm = (wave & 1) * 64, wn = (wave >> 1) * 64;
    int l16 = lane & 15, lq = lane >> 4;

    // XCD-aware remap (y fastest within each chunk)
    int nx = gridDim.x, ny = gridDim.y;
    int bx = blockIdx.x, by = blockIdx.y;
    int total = nx * ny;
    if ((total & 7) == 0) {
        int j = bx + nx * by;
        int w = (j & 7) * (total >> 3) + (j >> 3);
        bx = w / ny;
        by = w % ny;
    }
    int m0 = by * 128, n0 = bx * 128;

    // staging: 16KB per matrix-tile = 1024 x 16B units; unit u -> row r=u>>3,
    // slot s=u&7. Source col = (s ^ (r&7))*8 elements (involution).
    // wave covers units [wave*64 + i*256, +64) per call, i=0..3.
    const bf16_t* gA[4];
    const bf16_t* gB[4];
#pragma unroll
    for (int i = 0; i < 4; ++i) {
        int u = wave * 64 + lane + i * 256;
        int r = u >> 3, s = u & 7;
        int c = ((s ^ (r & 7)) << 3);
        gA[i] = Ab + (size_t)(m0 + r) * Kp + c;
        gB[i] = Bt + (size_t)(n0 + r) * Kp + c;
    }

    f32x4 acc[4][4] = {};
    int nt = Kp >> 6;

    // prologue: stage tile 0 into buf 0
    {
        bf16_t* dA = SH + wave * 512;
#pragma unroll
        for (int i = 0; i < 4; ++i) {
            gll16(gA[i], dA + i * 2048);
            gll16(gB[i], dA + 8192 + i * 2048);
            gA[i] += 64; gB[i] += 64;
        }
    }
    asm volatile("s_waitcnt vmcnt(0)" ::: "memory");
    asm volatile("s_barrier" ::: "memory");
    __builtin_amdgcn_sched_barrier(0);

    int bc = 0;
    for (int t = 0; t < nt; ++t) {
        if (t + 1 < nt) {
            // stage next tile into the buffer freed by the last barrier
            bf16_t* dA = SH + (bc ^ 1) * 16384 + wave * 512;
#pragma unroll
            for (int i = 0; i < 4; ++i) {
                gll16(gA[i], dA + i * 2048);
                gll16(gB[i], dA + 8192 + i * 2048);
                gA[i] += 64; gB[i] += 64;
            }
        }
        __builtin_amdgcn_sched_barrier(0);   // pin stage-issue ahead of ds_reads
        const bf16_t* rb = SH + bc * 16384;
        bf16x8 af[2][4], bfr[2][4];
#pragma unroll
        for (int kk = 0; kk < 2; ++kk) {
            int cs = (((kk * 4 + lq) ^ (l16 & 7)) << 3);
#pragma unroll
            for (int mi = 0; mi < 4; ++mi)
                af[kk][mi] = *(const bf16x8*)(rb + (wm + mi * 16 + l16) * 64 + cs);
#pragma unroll
            for (int ni = 0; ni < 4; ++ni)
                bfr[kk][ni] = *(const bf16x8*)(rb + 8192 + (wn + ni * 16 + l16) * 64 + cs);
        }
#pragma unroll
        for (int kk = 0; kk < 2; ++kk)
#pragma unroll
            for (int mi = 0; mi < 4; ++mi)
#pragma unroll
                for (int ni = 0; ni < 4; ++ni)
                    acc[mi][ni] = __builtin_amdgcn_mfma_f32_16x16x32_bf16(
                        af[kk][mi], bfr[kk][ni], acc[mi][ni], 0, 0, 0);
        // drain this iter's stage (window = ds_read+MFMA above); one barrier/tile
        asm volatile("s_waitcnt vmcnt(0) lgkmcnt(0)" ::: "memory");
        asm volatile("s_barrier" ::: "memory");
        __builtin_amdgcn_sched_barrier(0);
        bc ^= 1;
    }
    // loop's final barrier doubles as the pre-epilogue barrier (all reads retired)

    if (obf) {
        // ---- LDS re-layout epilogue: coalesced bf16x8 C stores ----
#pragma unroll
        for (int ni = 0; ni < 4; ++ni) {
            int cl = wn + ni * 16 + l16;
            float bv = bias[n0 + cl];
#pragma unroll
            for (int mi = 0; mi < 4; ++mi)
#pragma unroll
                for (int r = 0; r < 4; ++r) {
                    int rl = wm + mi * 16 + lq * 4 + r;
                    float v = acc[mi][ni][r] + bv;
                    if (act && v < 0.f) v *= 0.01f;
                    int slot = ((cl >> 3) ^ (rl & 7)) & 15;
                    SH[rl * 128 + slot * 8 + (cl & 7)] = (bf16_t)v;
                }
        }
        __syncthreads();
        bf16_t* Cb = (bf16_t*)Cm;
#pragma unroll
        for (int i = 0; i < 8; ++i) {
            int j = i * 2048 + tid * 8;       // bf16 index into SH
            int rl = j >> 7;
            int p = (j >> 3) & 15;
            int cl = ((p ^ (rl & 7)) & 15) * 8;
            bf16x8 v = *(const bf16x8*)(SH + rl * 128 + p * 8);
            int row = m0 + rl, col = n0 + cl;
            if (row < M) {
                if (col + 7 < Nsub) {
                    *(bf16x8*)(Cb + (size_t)row * Nsub + col) = v;
                } else {
#pragma unroll
                    for (int e = 0; e < 8; ++e)
                        if (col + e < Nsub) Cb[(size_t)row * Nsub + col + e] = v[e];
                }
            }
        }
    } else {
        // fp32 output path (decoder): direct stores
#pragma unroll
        for (int ni = 0; ni < 4; ++ni) {
            int col = n0 + wn + ni * 16 + l16;
            if (col >= Nsub) continue;
            float bv = bias[col];
#pragma unroll
            for (int mi = 0; mi < 4; ++mi)
#pragma unroll
                for (int r = 0; r < 4; ++r) {
                    int row = m0 + wm + mi * 16 + lq * 4 + r;
                    if (row < M) {
                        float v = acc[mi][ni][r] + bv;
                        if (act && v < 0.f) v *= 0.01f;
                        ((float*)Cm)[(size_t)row * Nsub + col] = v;
                    }
                }
        }
    }
}

// ------- fp32 GEMM (layer-1): 64x64 tile, 4x4/thread, BK=16 -------
#define TM 64
#define TN 64
#define TK 16
__global__ __launch_bounds__(256) void k_gemm(
        const float* __restrict__ A, const float* __restrict__ B,
        const float* __restrict__ bias, void* __restrict__ Cm,
        int M, int Nsub, int K, int ldb, int act, int obf) {
    __shared__ float As[TK][TM];
    __shared__ float Bs[TK][TN];
    int tid = threadIdx.x;
    int tx = tid % 16, ty = tid / 16;
    int m0 = blockIdx.y * TM, n0 = blockIdx.x * TN;
    float acc[4][4] = {};
    for (int k0 = 0; k0 < K; k0 += TK) {
#pragma unroll
        for (int i = 0; i < 4; ++i) {
            int idx = tid * 4 + i;
            int m = idx >> 4, k = idx & 15;
            float v = 0.f;
            if (k0 + k < K && m0 + m < M) v = A[(size_t)(m0 + m) * K + k0 + k];
            As[k][m] = v;
        }
#pragma unroll
        for (int i = 0; i < 4; ++i) {
            int idx = tid * 4 + i;
            int k = idx >> 6, n = idx & 63;
            float v = 0.f;
            if (k0 + k < K && n0 + n < Nsub) v = B[(size_t)(k0 + k) * ldb + n0 + n];
            Bs[k][n] = v;
        }
        __syncthreads();
#pragma unroll
        for (int kk = 0; kk < TK; ++kk) {
            float4 a4 = *(const float4*)&As[kk][ty * 4];
            float4 b4 = *(const float4*)&Bs[kk][tx * 4];
            float af[4] = {a4.x, a4.y, a4.z, a4.w};
            float bf[4] = {b4.x, b4.y, b4.z, b4.w};
#pragma unroll
            for (int i = 0; i < 4; ++i)
#pragma unroll
                for (int j = 0; j < 4; ++j)
                    acc[i][j] += af[i] * bf[j];
        }
        __syncthreads();
    }
#pragma unroll
    for (int i = 0; i < 4; ++i) {
        int m = m0 + ty * 4 + i;
        if (m >= M) continue;
#pragma unroll
        for (int j = 0; j < 4; ++j) {
            int n = n0 + tx * 4 + j;
            if (n < Nsub) {
                float v = acc[i][j] + bias[n];
                if (act && v < 0.f) v *= 0.01f;
                if (obf) ((bf16_t*)Cm)[(size_t)m * Nsub + n] = (bf16_t)v;
                else     ((float*)Cm)[(size_t)m * Nsub + n] = v;
            }
        }
    }
}

__global__ void k_gemm_naive(const float* __restrict__ A, const float* __restrict__ B,
                             const float* __restrict__ bias, float* __restrict__ out,
                             int M, int N, int K, int act) {
    int idx = blockIdx.x * 256 + threadIdx.x;
    if (idx >= M * N) return;
    int m = idx / N, n = idx % N;
    float s = bias[n];
    for (int k = 0; k < K; ++k)
        s += A[(size_t)m * K + k] * B[(size_t)k * N + n];
    if (act && s < 0.f) s *= 0.01f;
    out[idx] = s;
}

// ------- attention scores: one wave per (edge, local head), bf16x4 loads -------
__global__ void k_score(const bf16_t* __restrict__ xl, const bf16_t* __restrict__ xr,
                        const float* __restrict__ att, const int* __restrict__ srcA,
                        const int* __restrict__ dstA, float* __restrict__ sc,
                        int C, int HG, int h0) {
    int wid = (blockIdx.x * 256 + threadIdx.x) >> 6;
    int lane = threadIdx.x & 63;
    if (wid >= ETOT * HG) return;
    int e = wid / HG, hl = wid % HG;
    int s = srcA[e], d = dstA[e];
    const bf16x4* pl = (const bf16x4*)(xl + ((size_t)s * HG + hl) * C);
    const bf16x4* pr = (const bf16x4*)(xr + ((size_t)d * HG + hl) * C);
    const float4* pa = (const float4*)(att + (size_t)(h0 + hl) * C);
    float acc = 0.f;
    int C4 = C >> 2;
    for (int c = lane; c < C4; c += 64) {
        bf16x4 a = pl[c], b = pr[c];
        float4 w = pa[c];
        float v;
        v = (float)a[0] + (float)b[0]; v = v > 0.f ? v : 0.2f * v; acc += v * w.x;
        v = (float)a[1] + (float)b[1]; v = v > 0.f ? v : 0.2f * v; acc += v * w.y;
        v = (float)a[2] + (float)b[2]; v = v > 0.f ? v : 0.2f * v; acc += v * w.z;
        v = (float)a[3] + (float)b[3]; v = v > 0.f ? v : 0.2f * v; acc += v * w.w;
    }
#pragma unroll
    for (int off = 32; off; off >>= 1) acc += __shfl_down(acc, off, 64);
    if (lane == 0) sc[(size_t)e * HH + h0 + hl] = acc;
}

// ---------------- softmax per (dst, head) over incoming edges -----------------
__global__ void k_softmax(const int* __restrict__ off, const int* __restrict__ csre,
                          float* __restrict__ sc, int HG, int h0) {
    int idx = blockIdx.x * 256 + threadIdx.x;
    if (idx >= NN * HG) return;
    int d = idx / HG, h = h0 + idx % HG;
    int b = off[d], en = off[d + 1];
    float m = -1e30f;
    for (int i = b; i < en; ++i) m = fmaxf(m, sc[(size_t)csre[i] * HH + h]);
    float ssum = 0.f;
    for (int i = b; i < en; ++i) ssum += expf(sc[(size_t)csre[i] * HH + h] - m);
    float inv = 1.f / ssum;
    for (int i = b; i < en; ++i) {
        size_t p = (size_t)csre[i] * HH + h;
        sc[p] = expf(sc[p] - m) * inv;
    }
}

// ------- aggregate: block = (dst, c4-tile), thread = (hl, c4i) ---------------
__global__ __launch_bounds__(256) void k_aggregate(
        const bf16_t* __restrict__ xl, const float* __restrict__ sc,
        const int* __restrict__ off, const int* __restrict__ csre,
        const int* __restrict__ srcA, const float* __restrict__ bias,
        float* __restrict__ z, int C, int HG, int h0, int lgNC,
        int first, int last, int act) {
    __shared__ float4 sh[256];
    int d = blockIdx.x;
    int NC = 1 << lgNC;
    int c4i = threadIdx.x & (NC - 1);
    int hl = threadIdx.x >> lgNC;
    int c4 = blockIdx.y * NC + c4i;
    int C4 = C >> 2;
    bool active = (c4 < C4);
    float4 acc = {0.f, 0.f, 0.f, 0.f};
    int b = off[d], en = off[d + 1];
    for (int i = b; i < en; ++i) {
        int e = csre[i];
        int s = srcA[e];
        float w = sc[(size_t)e * HH + h0 + hl];
        if (active) {
            bf16x4 vx = *((const bf16x4*)(xl + ((size_t)s * HG + hl) * C) + c4);
            acc.x += w * (float)vx[0];
            acc.y += w * (float)vx[1];
            acc.z += w * (float)vx[2];
            acc.w += w * (float)vx[3];
        }
    }
    sh[threadIdx.x] = acc;
    __syncthreads();
    for (int s = HG >> 1; s >= 1; s >>= 1) {
        if (hl < s) {
            float4 o = sh[threadIdx.x + (s << lgNC)];
            float4 m = sh[threadIdx.x];
            m.x += o.x; m.y += o.y; m.z += o.z; m.w += o.w;
            sh[threadIdx.x] = m;
        }
        __syncthreads();
    }
    if (hl == 0 && active) {
        acc = sh[threadIdx.x];
        float4* zp = (float4*)(z + (size_t)d * C) + c4;
        if (!first) {
            float4 prev = *zp;
            acc.x += prev.x; acc.y += prev.y; acc.z += prev.z; acc.w += prev.w;
        }
        if (last) {
            const float4 bz = *((const float4*)bias + c4);
            acc.x = acc.x * (1.f / 32.f) + bz.x;
            acc.y = acc.y * (1.f / 32.f) + bz.y;
            acc.z = acc.z * (1.f / 32.f) + bz.z;
            acc.w = acc.w * (1.f / 32.f) + bz.w;
            if (act) {
                acc.x = acc.x < 0.f ? acc.x * 0.01f : acc.x;
                acc.y = acc.y < 0.f ? acc.y * 0.01f : acc.y;
                acc.z = acc.z < 0.f ? acc.z * 0.01f : acc.z;
                acc.w = acc.w < 0.f ? acc.w * 0.01f : acc.w;
            }
        }
        *zp = acc;
    }
}

// ---------------- host ----------------
extern "C" void kernel_launch(void* const* d_in, const int* in_sizes, int n_in,
                              void* d_out, int out_size, void* d_ws, size_t ws_size,
                              hipStream_t stream) {
    const float* x   = (const float*)d_in[0];
    const int* ei    = (const int*)d_in[1];
    const float* w1l = (const float*)d_in[2];  const float* b1l = (const float*)d_in[3];
    const float* w1r = (const float*)d_in[4];  const float* b1r = (const float*)d_in[5];
    const float* att1= (const float*)d_in[6];  const float* gb1 = (const float*)d_in[7];
    const float* w2l = (const float*)d_in[8];  const float* b2l = (const float*)d_in[9];
    const float* w2r = (const float*)d_in[10]; const float* b2r = (const float*)d_in[11];
    const float* att2= (const float*)d_in[12]; const float* gb2 = (const float*)d_in[13];
    const float* w3l = (const float*)d_in[14]; const float* b3l = (const float*)d_in[15];
    const float* w3r = (const float*)d_in[16]; const float* b3r = (const float*)d_in[17];
    const float* att3= (const float*)d_in[18]; const float* gb3 = (const float*)d_in[19];
    const float* dw1 = (const float*)d_in[20]; const float* db1 = (const float*)d_in[21];
    const float* dw2 = (const float*)d_in[22]; const float* db2 = (const float*)d_in[23];
    const float* dw3 = (const float*)d_in[24]; const float* db3 = (const float*)d_in[25];
    float* outp = (float*)d_out;

    char* p = (char*)d_ws;
    auto alloc = [&](size_t bytes) -> char* {
        char* r = p;
        p += (bytes + 255) & ~(size_t)255;
        return r;
    };
    float* sc   = (float*)alloc((size_t)ETOT * HH * 4);
    float* za   = (float*)alloc((size_t)NN * 1028 * 4);
    float* zb   = (float*)alloc((size_t)NN * 1028 * 4);
    bf16_t* Abf = (bf16_t*)alloc((size_t)NN * 1088 * 2);
    int*   ints = (int*)  alloc((size_t)(2 * NN + 16) * 4);
    int* cnt  = ints;
    int* cur  = ints + NN;
    int* flag = ints + 2 * NN;
    int* offp = (int*)alloc((size_t)(NN + 1) * 4);
    int* csre = (int*)alloc((size_t)ETOT * 4);
    int* srcA = (int*)alloc((size_t)ETOT * 4);
    int* dstA = (int*)alloc((size_t)ETOT * 4);
    size_t used = (size_t)(p - (char*)d_ws);
    size_t remain = (ws_size > used) ? (ws_size - used) : 0;
    char* chunk = p;

    k_zero_int<<<dim3((2 * NN + 16 + 255) / 256), dim3(256), 0, stream>>>(ints, 2 * NN + 16);
    k_detect<<<dim3((EE + 255) / 256), dim3(256), 0, stream>>>(ei, flag);
    k_edge_prep<<<dim3((ETOT + 255) / 256), dim3(256), 0, stream>>>(ei, flag, srcA, dstA, cnt);
    k_scan<<<dim3(1), dim3(NN), 0, stream>>>(cnt, offp);
    k_fill<<<dim3((ETOT + 255) / 256), dim3(256), 0, stream>>>(dstA, offp, cur, csre);

    struct Layer {
        const float* in; int cin; int C;
        const float *wl, *bl, *wr, *br, *att, *gb;
        float* zout; int act;
    };
    Layer L[3] = {
        { x,    4, 128,  w1l, b1l, w1r, b1r, att1, gb1, za, 1 },
        { za, 128, 512,  w2l, b2l, w2r, b2r, att2, gb2, zb, 1 },
        { zb, 512, 1028, w3l, b3l, w3r, b3r, att3, gb3, za, 0 },
    };
    auto al = [](size_t n) { return (n + 127) & ~(size_t)127; };

    for (int li = 0; li < 3; ++li) {
        int C = L[li].C, K = L[li].cin;
        bool mfma = (K >= 128);
        int Kp = (K + 63) & ~63;   // BK=64 alignment
        // per-head chunk bytes: xl + xr bf16 (+ Bt for mfma path)
        size_t perHG = 2ull * NN * C * 2 + (mfma ? (size_t)C * Kp * 2 : 0);
        int HG = 32;
        // 1MB slack: gload_lds staging may over-read up to one 128-row panel
        while (HG > 1 && (size_t)HG * perHG + (1u << 20) > remain) HG >>= 1;
        int nchunk = HH / HG;
        int lgNC = 0;
        while ((1 << lgNC) * HG < 256) ++lgNC;   // NC = 256/HG
        int NC = 1 << lgNC;
        bf16_t* xlc = (bf16_t*)chunk;
        bf16_t* xrc = xlc + al((size_t)NN * HG * C);
        bf16_t* Bt  = xrc + al((size_t)NN * HG * C);

        if (mfma)
            k_convA<<<dim3((NN * Kp + 255) / 256), dim3(256), 0, stream>>>(L[li].in, Abf, NN, K, Kp);

        for (int hg = 0; hg < nchunk; ++hg) {
            int h0 = hg * HG;
            int colOff = h0 * C;
            int Nsub = HG * C;
            if (mfma) {
                dim3 gc((Nsub + 31) / 32, Kp / 32);
                dim3 gg((Nsub + 127) / 128, NN / 128);
                k_convB<<<gc, dim3(256), 0, stream>>>(L[li].wl + colOff, Bt, K, Nsub, HH * C, Kp);
                k_gemm_bf16<<<gg, dim3(256), 0, stream>>>(Abf, Bt, L[li].bl + colOff, xlc, NN, Nsub, Kp, 0, 1);
                k_convB<<<gc, dim3(256), 0, stream>>>(L[li].wr + colOff, Bt, K, Nsub, HH * C, Kp);
                k_gemm_bf16<<<gg, dim3(256), 0, stream>>>(Abf, Bt, L[li].br + colOff, xrc, NN, Nsub, Kp, 0, 1);
            } else {
                dim3 gg((Nsub + TN - 1) / TN, (NN + TM - 1) / TM);
                k_gemm<<<gg, dim3(256), 0, stream>>>(L[li].in, L[li].wl + colOff, L[li].bl + colOff,
                                                     xlc, NN, Nsub, K, HH * C, 0, 1);
                k_gemm<<<gg, dim3(256), 0, stream>>>(L[li].in, L[li].wr + colOff, L[li].br + colOff,
                                                     xrc, NN, Nsub, K, HH * C, 0, 1);
            }
            int waves = ETOT * HG;
            k_score<<<dim3((waves * 64 + 255) / 256), dim3(256), 0, stream>>>(
                xlc, xrc, L[li].att, srcA, dstA, sc, C, HG, h0);
            k_softmax<<<dim3((NN * HG + 255) / 256), dim3(256), 0, stream>>>(offp, csre, sc, HG, h0);
            int C4 = C >> 2;
            dim3 ga(NN, (C4 + NC - 1) / NC);
            k_aggregate<<<ga, dim3(256), 0, stream>>>(xlc, sc, offp, csre, srcA, L[li].gb,
                                                      L[li].zout, C, HG, h0, lgNC,
                                                      hg == 0, hg == nchunk - 1, L[li].act);
        }
    }

    // ---- decoder: all three layers on the MFMA path ----
    {
        // chunk layout: Bt1 (512x1088 bf16) | AbD2 (1024x512 bf16) | Bt2 (128x512 bf16)
        bf16_t* Bt1  = (bf16_t*)chunk;
        bf16_t* AbD2 = Bt1 + al((size_t)512 * 1088);
        bf16_t* Bt2  = AbD2 + al((size_t)NN * 512);

        // decoder-1: 1028 -> 512, LeakyReLU, bf16 output straight into AbD2
        k_convA<<<dim3((NN * 1088 + 255) / 256), dim3(256), 0, stream>>>(za, Abf, NN, 1028, 1088);
        k_convB<<<dim3(512 / 32, 1088 / 32), dim3(256), 0, stream>>>(dw1, Bt1, 1028, 512, 512, 1088);
        k_gemm_bf16<<<dim3(512 / 128, NN / 128), dim3(256), 0, stream>>>(Abf, Bt1, db1, AbD2, NN, 512, 1088, 1, 1);

        // decoder-2: 512 -> 128, LeakyReLU, fp32 output into za
        k_convB<<<dim3(128 / 32, 512 / 32), dim3(256), 0, stream>>>(dw2, Bt2, 512, 128, 128, 512);
        k_gemm_bf16<<<dim3(128 / 128, NN / 128), dim3(256), 0, stream>>>(AbD2, Bt2, db2, za, NN, 128, 512, 1, 0);
    }
    k_gemm_naive<<<dim3((NN * 2 + 255) / 256), dim3(256), 0, stream>>>(za, dw3, db3, outp, NN, 2, 128, 0);
}